// Round 1
// baseline (2575.037 us; speedup 1.0000x reference)
//
#include <hip/hip_runtime.h>

#define N_NODES 20000
#define N_EDGES 320000
#define C 64
#define NATTR 10
#define MSG_DIM 576      // C*(1+3+5)
#define WC_COLS 192      // 3*C

// ---------------------------------------------------------------------------
// Kernel 1: collapse the (linear) radial MLP into Wc (8 x 192), one block.
// Wc = (Wr0/sqrt(8)) @ (Wr1/8) @ (Wr2/8) @ (Wr3/8)
// ---------------------------------------------------------------------------
__global__ void combine_radial(const float* __restrict__ Wr0,
                               const float* __restrict__ Wr1,
                               const float* __restrict__ Wr2,
                               const float* __restrict__ Wr3,
                               float* __restrict__ Wc) {
    __shared__ float T[8 * 64];
    __shared__ float T2[8 * 64];
    const int t = threadIdx.x;  // 256
    const float s0 = 0.35355339059327373f;  // 1/sqrt(8)
    const float s1 = 0.125f;                // 1/8

    // T = Wr0 @ Wr1  (8x64)
    for (int i = t; i < 8 * 64; i += 256) {
        int r = i >> 6, c = i & 63;
        float acc = 0.f;
        for (int k = 0; k < 64; ++k) acc += Wr0[r * 64 + k] * Wr1[k * 64 + c];
        T[i] = acc * (s0 * s1);
    }
    __syncthreads();
    // T2 = T @ Wr2  (8x64)
    for (int i = t; i < 8 * 64; i += 256) {
        int r = i >> 6, c = i & 63;
        float acc = 0.f;
        for (int k = 0; k < 64; ++k) acc += T[r * 64 + k] * Wr2[k * 64 + c];
        T2[i] = acc * s1;
    }
    __syncthreads();
    // Wc = T2 @ Wr3  (8x192)
    for (int i = t; i < 8 * WC_COLS; i += 256) {
        int r = i / WC_COLS, c = i % WC_COLS;
        float acc = 0.f;
        for (int k = 0; k < 64; ++k) acc += T2[r * 64 + k] * Wr3[k * WC_COLS + c];
        Wc[i] = acc * s1;
    }
}

// ---------------------------------------------------------------------------
// Kernel 2: h = node_feats @ (W_lin1 / 8).  16 nodes / block, 1 node / wave iter.
// ---------------------------------------------------------------------------
__global__ void node_linear(const float* __restrict__ nf,
                            const float* __restrict__ W,
                            float* __restrict__ h) {
    __shared__ float Ws[64 * 64];
    __shared__ float row[4][64];
    const int t = threadIdx.x, lane = t & 63, wv = t >> 6;
    for (int i = t; i < 4096; i += 256) Ws[i] = W[i] * 0.125f;
    __syncthreads();
    const int base = blockIdx.x * 16;
    for (int it = 0; it < 4; ++it) {
        int n = base + it * 4 + wv;
        if (n >= N_NODES) break;
        row[wv][lane] = nf[(size_t)n * 64 + lane];
        float acc = 0.f;
        #pragma unroll
        for (int k = 0; k < 64; ++k) acc += row[wv][k] * Ws[k * 64 + lane];
        h[(size_t)n * 64 + lane] = acc;
    }
}

// ---------------------------------------------------------------------------
// Kernel 3: per-edge message + atomic scatter into msg (= out buffer).
// One wave per edge, 8 edges per wave, 4 waves per block.
// ---------------------------------------------------------------------------
__global__ void edge_kernel(const float* __restrict__ ef,   // E x 8
                            const float* __restrict__ ea,   // E x 9
                            const int* __restrict__ eidx,   // 2 x E
                            const float* __restrict__ h,    // N x 64
                            const float* __restrict__ Wc,   // 8 x 192
                            float* __restrict__ msg) {      // N x 576
    __shared__ float WcL[8 * WC_COLS];
    const int t = threadIdx.x, lane = t & 63, wv = t >> 6;
    for (int i = t; i < 8 * WC_COLS; i += 256) WcL[i] = Wc[i];
    __syncthreads();

    const int ebase = blockIdx.x * 32 + wv * 8;
    for (int i = 0; i < 8; ++i) {
        const int e = ebase + i;
        if (e >= N_EDGES) break;
        const int s = eidx[e];
        const int r = eidx[N_EDGES + e];

        // radial weights for this edge (3 values per lane/channel)
        float w0 = 0.f, w1 = 0.f, w2 = 0.f;
        #pragma unroll
        for (int k = 0; k < 8; ++k) {
            const float f = ef[(size_t)e * 8 + k];   // wave-uniform
            w0 += f * WcL[k * WC_COLS + lane];
            w1 += f * WcL[k * WC_COLS + 64 + lane];
            w2 += f * WcL[k * WC_COLS + 128 + lane];
        }
        const float xs = h[(size_t)s * 64 + lane];
        const float a0 = xs * w0, a1 = xs * w1, a2 = xs * w2;
        const float* y = ea + (size_t)e * 9;   // wave-uniform
        float* mrow = msg + (size_t)r * MSG_DIM;

        unsafeAtomicAdd(mrow + lane, a0 * y[0]);
        float* m1 = mrow + 64 + lane * 3;
        unsafeAtomicAdd(m1 + 0, a1 * y[1]);
        unsafeAtomicAdd(m1 + 1, a1 * y[2]);
        unsafeAtomicAdd(m1 + 2, a1 * y[3]);
        float* m2 = mrow + 256 + lane * 5;
        unsafeAtomicAdd(m2 + 0, a2 * y[4]);
        unsafeAtomicAdd(m2 + 1, a2 * y[5]);
        unsafeAtomicAdd(m2 + 2, a2 * y[6]);
        unsafeAtomicAdd(m2 + 3, a2 * y[7]);
        unsafeAtomicAdd(m2 + 4, a2 * y[8]);
    }
}

// ---------------------------------------------------------------------------
// Kernel 4: per-node W_msg transform, in place on the msg/out buffer.
// out[n,v,m] = (1/(8*16)) * sum_u msg_l[n,u,m] * W_msg[l][u][v]
// 64 nodes / block (16 iters x 4 waves), W_msg staged in LDS (48 KB).
// ---------------------------------------------------------------------------
__global__ void out_transform(const float* __restrict__ Wmsg,  // 3*64*64
                              float* __restrict__ out) {       // N x 576 (in = msg)
    __shared__ float WL[3 * 64 * 64];
    __shared__ float mrow[4][MSG_DIM];
    const int t = threadIdx.x, lane = t & 63, wv = t >> 6;
    for (int i = t; i < 3 * 64 * 64; i += 256) WL[i] = Wmsg[i];
    __syncthreads();
    const float scale = 1.f / 128.f;  // 1/(sqrt(64)*16)

    for (int it = 0; it < 16; ++it) {
        const int n = blockIdx.x * 64 + it * 4 + wv;
        if (n >= N_NODES) return;
        float* rowp = out + (size_t)n * MSG_DIM;
        for (int i = lane; i < MSG_DIM; i += 64) mrow[wv][i] = rowp[i];

        float o[9];
        {   // l = 0, d = 1
            float acc = 0.f;
            #pragma unroll
            for (int u = 0; u < 64; ++u) acc += mrow[wv][u] * WL[u * 64 + lane];
            o[0] = acc;
        }
        #pragma unroll
        for (int m = 0; m < 3; ++m) {  // l = 1, d = 3
            float acc = 0.f;
            for (int u = 0; u < 64; ++u)
                acc += mrow[wv][64 + u * 3 + m] * WL[4096 + u * 64 + lane];
            o[1 + m] = acc;
        }
        #pragma unroll
        for (int m = 0; m < 5; ++m) {  // l = 2, d = 5
            float acc = 0.f;
            for (int u = 0; u < 64; ++u)
                acc += mrow[wv][256 + u * 5 + m] * WL[8192 + u * 64 + lane];
            o[4 + m] = acc;
        }
        float* op = rowp + lane * 9;
        #pragma unroll
        for (int m = 0; m < 9; ++m) op[m] = o[m] * scale;
    }
}

// ---------------------------------------------------------------------------
// Kernel 5: sc[n,w] = sum_{u,v} h[n,u]*attrs[n,v]*W_skip[u,v,w] / sqrt(640)
// 32 nodes / block; thread = (lane=w, wv); 8 node-accumulators per thread.
// ---------------------------------------------------------------------------
__global__ void skip_kernel(const float* __restrict__ h,
                            const float* __restrict__ attrs,
                            const float* __restrict__ Wskip,  // 64*10*64
                            float* __restrict__ sc) {
    __shared__ float hl[32 * 64];
    __shared__ float al[32 * NATTR];
    const int t = threadIdx.x, lane = t & 63, wv = t >> 6;
    const int nb = blockIdx.x * 32;
    for (int i = t; i < 32 * 64; i += 256) hl[i] = h[(size_t)(nb + (i >> 6)) * 64 + (i & 63)];
    for (int i = t; i < 32 * NATTR; i += 256) al[i] = attrs[(size_t)(nb + i / NATTR) * NATTR + i % NATTR];
    __syncthreads();

    float acc[8] = {0.f, 0.f, 0.f, 0.f, 0.f, 0.f, 0.f, 0.f};
    for (int u = 0; u < 64; ++u) {
        #pragma unroll
        for (int v = 0; v < NATTR; ++v) {
            const float wk = Wskip[(u * NATTR + v) * 64 + lane];
            #pragma unroll
            for (int i = 0; i < 8; ++i) {
                const int nl = wv + 4 * i;
                acc[i] += hl[nl * 64 + u] * al[nl * NATTR + v] * wk;
            }
        }
    }
    const float scale = 0.03952847075210474f;  // 1/sqrt(640)
    #pragma unroll
    for (int i = 0; i < 8; ++i)
        sc[(size_t)(nb + wv + 4 * i) * 64 + lane] = acc[i] * scale;
}

// ---------------------------------------------------------------------------
extern "C" void kernel_launch(void* const* d_in, const int* in_sizes, int n_in,
                              void* d_out, int out_size, void* d_ws, size_t ws_size,
                              hipStream_t stream) {
    const float* node_attrs = (const float*)d_in[0];
    const float* node_feats = (const float*)d_in[1];
    const float* edge_attrs = (const float*)d_in[2];
    const float* edge_feats = (const float*)d_in[3];
    const int*   edge_index = (const int*)d_in[4];
    const float* W_lin1 = (const float*)d_in[5];
    const float* W_r0 = (const float*)d_in[6];
    const float* W_r1 = (const float*)d_in[7];
    const float* W_r2 = (const float*)d_in[8];
    const float* W_r3 = (const float*)d_in[9];
    const float* W_msg = (const float*)d_in[10];
    const float* W_skip = (const float*)d_in[11];

    float* out = (float*)d_out;                       // N x 576 (msg, then transformed in place)
    float* sc  = out + (size_t)N_NODES * MSG_DIM;     // N x 64

    float* wsf = (float*)d_ws;
    float* Wc = wsf;                   // 1536 floats (pad to 2048)
    float* h  = wsf + 2048;            // N x 64

    combine_radial<<<1, 256, 0, stream>>>(W_r0, W_r1, W_r2, W_r3, Wc);
    node_linear<<<1250, 256, 0, stream>>>(node_feats, W_lin1, h);
    hipMemsetAsync(out, 0, (size_t)N_NODES * MSG_DIM * sizeof(float), stream);
    edge_kernel<<<10000, 256, 0, stream>>>(edge_feats, edge_attrs, edge_index, h, Wc, out);
    out_transform<<<313, 256, 0, stream>>>(W_msg, out);
    skip_kernel<<<625, 256, 0, stream>>>(h, node_attrs, W_skip, sc);
}

// Round 2
// 429.931 us; speedup vs baseline: 5.9894x; 5.9894x over previous
//
#include <hip/hip_runtime.h>

#define N_NODES 20000
#define N_EDGES 320000
#define C 64
#define NATTR 10
#define MSG_DIM 576      // C*(1+3+5)
#define WC_COLS 192      // 3*C

// ---------------------------------------------------------------------------
// Kernel 1: collapse the (linear) radial MLP into Wc (8 x 192), one block.
// ---------------------------------------------------------------------------
__global__ void combine_radial(const float* __restrict__ Wr0,
                               const float* __restrict__ Wr1,
                               const float* __restrict__ Wr2,
                               const float* __restrict__ Wr3,
                               float* __restrict__ Wc) {
    __shared__ float T[8 * 64];
    __shared__ float T2[8 * 64];
    const int t = threadIdx.x;  // 256
    const float s0 = 0.35355339059327373f;  // 1/sqrt(8)
    const float s1 = 0.125f;                // 1/8

    for (int i = t; i < 8 * 64; i += 256) {
        int r = i >> 6, c = i & 63;
        float acc = 0.f;
        for (int k = 0; k < 64; ++k) acc += Wr0[r * 64 + k] * Wr1[k * 64 + c];
        T[i] = acc * (s0 * s1);
    }
    __syncthreads();
    for (int i = t; i < 8 * 64; i += 256) {
        int r = i >> 6, c = i & 63;
        float acc = 0.f;
        for (int k = 0; k < 64; ++k) acc += T[r * 64 + k] * Wr2[k * 64 + c];
        T2[i] = acc * s1;
    }
    __syncthreads();
    for (int i = t; i < 8 * WC_COLS; i += 256) {
        int r = i / WC_COLS, c = i % WC_COLS;
        float acc = 0.f;
        for (int k = 0; k < 64; ++k) acc += T2[r * 64 + k] * Wr3[k * WC_COLS + c];
        Wc[i] = acc * s1;
    }
}

// ---------------------------------------------------------------------------
// Kernel 2: h = node_feats @ (W_lin1 / 8).
// ---------------------------------------------------------------------------
__global__ void node_linear(const float* __restrict__ nf,
                            const float* __restrict__ W,
                            float* __restrict__ h) {
    __shared__ float Ws[64 * 64];
    __shared__ float row[4][64];
    const int t = threadIdx.x, lane = t & 63, wv = t >> 6;
    for (int i = t; i < 4096; i += 256) Ws[i] = W[i] * 0.125f;
    __syncthreads();
    const int base = blockIdx.x * 16;
    for (int it = 0; it < 4; ++it) {
        int n = base + it * 4 + wv;
        if (n >= N_NODES) break;
        row[wv][lane] = nf[(size_t)n * 64 + lane];
        float acc = 0.f;
        #pragma unroll
        for (int k = 0; k < 64; ++k) acc += row[wv][k] * Ws[k * 64 + lane];
        h[(size_t)n * 64 + lane] = acc;
    }
}

// ---------------------------------------------------------------------------
// Sort-by-receiver pipeline: histogram -> scan -> scatter (counting sort).
// ---------------------------------------------------------------------------
__global__ void hist_kernel(const int* __restrict__ eidx, int* __restrict__ counts) {
    const int e = blockIdx.x * 256 + threadIdx.x;
    if (e < N_EDGES) atomicAdd(&counts[eidx[N_EDGES + e]], 1);
}

// One block, 256 threads. Exclusive prefix sum of counts[20000] -> start, cursor.
#define SCAN_CHUNK 79   // ceil(20000/256) = 79
__global__ void scan_kernel(const int* __restrict__ counts,
                            int* __restrict__ start, int* __restrict__ cursor) {
    __shared__ int tot[256];
    __shared__ int pre[256];
    const int t = threadIdx.x;
    const int base = t * SCAN_CHUNK;
    int s = 0;
    for (int j = 0; j < SCAN_CHUNK; ++j) {
        int idx = base + j;
        if (idx < N_NODES) s += counts[idx];
    }
    tot[t] = s;
    __syncthreads();
    if (t == 0) {
        int a = 0;
        for (int i = 0; i < 256; ++i) { pre[i] = a; a += tot[i]; }
    }
    __syncthreads();
    int a = pre[t];
    for (int j = 0; j < SCAN_CHUNK; ++j) {
        int idx = base + j;
        if (idx < N_NODES) {
            start[idx] = a;
            cursor[idx] = a;
            a += counts[idx];
        }
    }
}

__global__ void scatter_kernel(const int* __restrict__ eidx,
                               int* __restrict__ cursor, int* __restrict__ perm) {
    const int e = blockIdx.x * 256 + threadIdx.x;
    if (e < N_EDGES) {
        const int r = eidx[N_EDGES + e];
        const int pos = atomicAdd(&cursor[r], 1);
        perm[pos] = e;
    }
}

// ---------------------------------------------------------------------------
// Kernel 3: gather — one wave per node; accumulate messages in registers,
// write the 576-float msg row once (no float atomics).
// ---------------------------------------------------------------------------
__global__ void gather_kernel(const float* __restrict__ ef,   // E x 8
                              const float* __restrict__ ea,   // E x 9
                              const int* __restrict__ eidx,   // 2 x E (senders at [0,E))
                              const float* __restrict__ h,    // N x 64
                              const float* __restrict__ Wc,   // 8 x 192
                              const int* __restrict__ start,
                              const int* __restrict__ counts,
                              const int* __restrict__ perm,
                              float* __restrict__ msg) {      // N x 576
    __shared__ float WcL[8 * WC_COLS];
    const int t = threadIdx.x, lane = t & 63, wv = t >> 6;
    for (int i = t; i < 8 * WC_COLS; i += 256) WcL[i] = Wc[i];
    __syncthreads();

    const int n = blockIdx.x * 4 + wv;
    if (n >= N_NODES) return;
    const int s0 = start[n], cnt = counts[n];

    float p0 = 0.f;
    float p1[3] = {0.f, 0.f, 0.f};
    float p2[5] = {0.f, 0.f, 0.f, 0.f, 0.f};

    for (int j = 0; j < cnt; ++j) {
        const int e = perm[s0 + j];
        const int snd = eidx[e];
        const float xs = h[(size_t)snd * 64 + lane];

        // radial weights (ef row is 32B-aligned -> two float4 broadcast loads)
        const float4* ef4 = reinterpret_cast<const float4*>(ef + (size_t)e * 8);
        const float4 fa = ef4[0], fb = ef4[1];
        float w0, w1, w2;
        {
            const float* fk = reinterpret_cast<const float*>(&fa);
            w0 = fk[0] * WcL[0 * WC_COLS + lane];
            w1 = fk[0] * WcL[0 * WC_COLS + 64 + lane];
            w2 = fk[0] * WcL[0 * WC_COLS + 128 + lane];
            #pragma unroll
            for (int k = 1; k < 4; ++k) {
                w0 += fk[k] * WcL[k * WC_COLS + lane];
                w1 += fk[k] * WcL[k * WC_COLS + 64 + lane];
                w2 += fk[k] * WcL[k * WC_COLS + 128 + lane];
            }
            const float* gk = reinterpret_cast<const float*>(&fb);
            #pragma unroll
            for (int k = 0; k < 4; ++k) {
                w0 += gk[k] * WcL[(k + 4) * WC_COLS + lane];
                w1 += gk[k] * WcL[(k + 4) * WC_COLS + 64 + lane];
                w2 += gk[k] * WcL[(k + 4) * WC_COLS + 128 + lane];
            }
        }
        const float* y = ea + (size_t)e * 9;   // wave-uniform, 4B-aligned only
        const float a0 = xs * w0, a1 = xs * w1, a2 = xs * w2;
        p0    += a0 * y[0];
        p1[0] += a1 * y[1];
        p1[1] += a1 * y[2];
        p1[2] += a1 * y[3];
        p2[0] += a2 * y[4];
        p2[1] += a2 * y[5];
        p2[2] += a2 * y[6];
        p2[3] += a2 * y[7];
        p2[4] += a2 * y[8];
    }

    float* mrow = msg + (size_t)n * MSG_DIM;
    mrow[lane] = p0;
    #pragma unroll
    for (int m = 0; m < 3; ++m) mrow[64 + lane * 3 + m] = p1[m];
    #pragma unroll
    for (int m = 0; m < 5; ++m) mrow[256 + lane * 5 + m] = p2[m];
}

// ---------------------------------------------------------------------------
// Kernel 4: per-node W_msg transform, in place on the msg/out buffer.
// ---------------------------------------------------------------------------
__global__ void out_transform(const float* __restrict__ Wmsg,  // 3*64*64
                              float* __restrict__ out) {       // N x 576 (in = msg)
    __shared__ float WL[3 * 64 * 64];
    __shared__ float mrow[4][MSG_DIM];
    const int t = threadIdx.x, lane = t & 63, wv = t >> 6;
    for (int i = t; i < 3 * 64 * 64; i += 256) WL[i] = Wmsg[i];
    __syncthreads();
    const float scale = 1.f / 128.f;  // 1/(sqrt(64)*16)

    for (int it = 0; it < 16; ++it) {
        const int n = blockIdx.x * 64 + it * 4 + wv;
        if (n >= N_NODES) return;
        float* rowp = out + (size_t)n * MSG_DIM;
        for (int i = lane; i < MSG_DIM; i += 64) mrow[wv][i] = rowp[i];

        float o[9];
        {
            float acc = 0.f;
            #pragma unroll
            for (int u = 0; u < 64; ++u) acc += mrow[wv][u] * WL[u * 64 + lane];
            o[0] = acc;
        }
        #pragma unroll
        for (int m = 0; m < 3; ++m) {
            float acc = 0.f;
            for (int u = 0; u < 64; ++u)
                acc += mrow[wv][64 + u * 3 + m] * WL[4096 + u * 64 + lane];
            o[1 + m] = acc;
        }
        #pragma unroll
        for (int m = 0; m < 5; ++m) {
            float acc = 0.f;
            for (int u = 0; u < 64; ++u)
                acc += mrow[wv][256 + u * 5 + m] * WL[8192 + u * 64 + lane];
            o[4 + m] = acc;
        }
        float* op = rowp + lane * 9;
        #pragma unroll
        for (int m = 0; m < 9; ++m) op[m] = o[m] * scale;
    }
}

// ---------------------------------------------------------------------------
// Kernel 5: sc[n,w] = sum_{u,v} h[n,u]*attrs[n,v]*W_skip[u,v,w] / sqrt(640)
// ---------------------------------------------------------------------------
__global__ void skip_kernel(const float* __restrict__ h,
                            const float* __restrict__ attrs,
                            const float* __restrict__ Wskip,  // 64*10*64
                            float* __restrict__ sc) {
    __shared__ float hl[32 * 64];
    __shared__ float al[32 * NATTR];
    const int t = threadIdx.x, lane = t & 63, wv = t >> 6;
    const int nb = blockIdx.x * 32;
    for (int i = t; i < 32 * 64; i += 256) hl[i] = h[(size_t)(nb + (i >> 6)) * 64 + (i & 63)];
    for (int i = t; i < 32 * NATTR; i += 256) al[i] = attrs[(size_t)(nb + i / NATTR) * NATTR + i % NATTR];
    __syncthreads();

    float acc[8] = {0.f, 0.f, 0.f, 0.f, 0.f, 0.f, 0.f, 0.f};
    for (int u = 0; u < 64; ++u) {
        #pragma unroll
        for (int v = 0; v < NATTR; ++v) {
            const float wk = Wskip[(u * NATTR + v) * 64 + lane];
            #pragma unroll
            for (int i = 0; i < 8; ++i) {
                const int nl = wv + 4 * i;
                acc[i] += hl[nl * 64 + u] * al[nl * NATTR + v] * wk;
            }
        }
    }
    const float scale = 0.03952847075210474f;  // 1/sqrt(640)
    #pragma unroll
    for (int i = 0; i < 8; ++i)
        sc[(size_t)(nb + wv + 4 * i) * 64 + lane] = acc[i] * scale;
}

// ---------------------------------------------------------------------------
extern "C" void kernel_launch(void* const* d_in, const int* in_sizes, int n_in,
                              void* d_out, int out_size, void* d_ws, size_t ws_size,
                              hipStream_t stream) {
    const float* node_attrs = (const float*)d_in[0];
    const float* node_feats = (const float*)d_in[1];
    const float* edge_attrs = (const float*)d_in[2];
    const float* edge_feats = (const float*)d_in[3];
    const int*   edge_index = (const int*)d_in[4];
    const float* W_lin1 = (const float*)d_in[5];
    const float* W_r0 = (const float*)d_in[6];
    const float* W_r1 = (const float*)d_in[7];
    const float* W_r2 = (const float*)d_in[8];
    const float* W_r3 = (const float*)d_in[9];
    const float* W_msg = (const float*)d_in[10];
    const float* W_skip = (const float*)d_in[11];

    float* out = (float*)d_out;                       // N x 576 (msg, transformed in place)
    float* sc  = out + (size_t)N_NODES * MSG_DIM;     // N x 64

    // workspace layout (floats then ints, all 4B)
    float* wsf = (float*)d_ws;
    float* Wc = wsf;                          // 1536 floats (pad to 2048)
    float* h  = wsf + 2048;                   // N*64 = 1,280,000 floats
    int* wsi   = (int*)(wsf + 2048 + (size_t)N_NODES * 64);
    int* counts = wsi;                        // N
    int* start  = wsi + N_NODES;              // N
    int* cursor = wsi + 2 * N_NODES;          // N
    int* perm   = wsi + 3 * N_NODES;          // E

    combine_radial<<<1, 256, 0, stream>>>(W_r0, W_r1, W_r2, W_r3, Wc);
    node_linear<<<1250, 256, 0, stream>>>(node_feats, W_lin1, h);

    hipMemsetAsync(counts, 0, N_NODES * sizeof(int), stream);
    hist_kernel<<<(N_EDGES + 255) / 256, 256, 0, stream>>>(edge_index, counts);
    scan_kernel<<<1, 256, 0, stream>>>(counts, start, cursor);
    scatter_kernel<<<(N_EDGES + 255) / 256, 256, 0, stream>>>(edge_index, cursor, perm);

    gather_kernel<<<(N_NODES + 3) / 4, 256, 0, stream>>>(
        edge_feats, edge_attrs, edge_index, h, Wc, start, counts, perm, out);

    out_transform<<<313, 256, 0, stream>>>(W_msg, out);
    skip_kernel<<<625, 256, 0, stream>>>(h, node_attrs, W_skip, sc);
}

// Round 3
// 393.072 us; speedup vs baseline: 6.5511x; 1.0938x over previous
//
#include <hip/hip_runtime.h>

#define N_NODES 20000
#define N_EDGES 320000
#define C 64
#define NATTR 10
#define MSG_DIM 576      // C*(1+3+5)
#define WC_COLS 192      // 3*C

// ---------------------------------------------------------------------------
// Kernel 1: collapse the (linear) radial MLP into Wc (8 x 192), one block.
// ---------------------------------------------------------------------------
__global__ void combine_radial(const float* __restrict__ Wr0,
                               const float* __restrict__ Wr1,
                               const float* __restrict__ Wr2,
                               const float* __restrict__ Wr3,
                               float* __restrict__ Wc) {
    __shared__ float T[8 * 64];
    __shared__ float T2[8 * 64];
    const int t = threadIdx.x;  // 256
    const float s0 = 0.35355339059327373f;  // 1/sqrt(8)
    const float s1 = 0.125f;                // 1/8

    for (int i = t; i < 8 * 64; i += 256) {
        int r = i >> 6, c = i & 63;
        float acc = 0.f;
        for (int k = 0; k < 64; ++k) acc += Wr0[r * 64 + k] * Wr1[k * 64 + c];
        T[i] = acc * (s0 * s1);
    }
    __syncthreads();
    for (int i = t; i < 8 * 64; i += 256) {
        int r = i >> 6, c = i & 63;
        float acc = 0.f;
        for (int k = 0; k < 64; ++k) acc += T[r * 64 + k] * Wr2[k * 64 + c];
        T2[i] = acc * s1;
    }
    __syncthreads();
    for (int i = t; i < 8 * WC_COLS; i += 256) {
        int r = i / WC_COLS, c = i % WC_COLS;
        float acc = 0.f;
        for (int k = 0; k < 64; ++k) acc += T2[r * 64 + k] * Wr3[k * WC_COLS + c];
        Wc[i] = acc * s1;
    }
}

// ---------------------------------------------------------------------------
// Kernel 2: h = node_feats @ (W_lin1 / 8).
// ---------------------------------------------------------------------------
__global__ void node_linear(const float* __restrict__ nf,
                            const float* __restrict__ W,
                            float* __restrict__ h) {
    __shared__ float Ws[64 * 64];
    __shared__ float row[4][64];
    const int t = threadIdx.x, lane = t & 63, wv = t >> 6;
    for (int i = t; i < 4096; i += 256) Ws[i] = W[i] * 0.125f;
    __syncthreads();
    const int base = blockIdx.x * 16;
    for (int it = 0; it < 4; ++it) {
        int n = base + it * 4 + wv;
        if (n >= N_NODES) break;
        row[wv][lane] = nf[(size_t)n * 64 + lane];
        float acc = 0.f;
        #pragma unroll
        for (int k = 0; k < 64; ++k) acc += row[wv][k] * Ws[k * 64 + lane];
        h[(size_t)n * 64 + lane] = acc;
    }
}

// ---------------------------------------------------------------------------
// Sort-by-receiver pipeline: histogram -> scan -> scatter (counting sort).
// ---------------------------------------------------------------------------
__global__ void hist_kernel(const int* __restrict__ eidx, int* __restrict__ counts) {
    const int e = blockIdx.x * 256 + threadIdx.x;
    if (e < N_EDGES) atomicAdd(&counts[eidx[N_EDGES + e]], 1);
}

#define SCAN_CHUNK 79   // ceil(20000/256) = 79
__global__ void scan_kernel(const int* __restrict__ counts,
                            int* __restrict__ start, int* __restrict__ cursor) {
    __shared__ int tot[256];
    __shared__ int pre[256];
    const int t = threadIdx.x;
    const int base = t * SCAN_CHUNK;
    int s = 0;
    for (int j = 0; j < SCAN_CHUNK; ++j) {
        int idx = base + j;
        if (idx < N_NODES) s += counts[idx];
    }
    tot[t] = s;
    __syncthreads();
    if (t == 0) {
        int a = 0;
        for (int i = 0; i < 256; ++i) { pre[i] = a; a += tot[i]; }
    }
    __syncthreads();
    int a = pre[t];
    for (int j = 0; j < SCAN_CHUNK; ++j) {
        int idx = base + j;
        if (idx < N_NODES) {
            start[idx] = a;
            cursor[idx] = a;
            a += counts[idx];
        }
    }
}

__global__ void scatter_kernel(const int* __restrict__ eidx,
                               int* __restrict__ cursor, int* __restrict__ perm) {
    const int e = blockIdx.x * 256 + threadIdx.x;
    if (e < N_EDGES) {
        const int r = eidx[N_EDGES + e];
        const int pos = atomicAdd(&cursor[r], 1);
        perm[pos] = e;
    }
}

// ---------------------------------------------------------------------------
// Kernel 3: gather — one wave per node; accumulate messages in registers,
// write the 576-float msg row once (no float atomics).
// ---------------------------------------------------------------------------
__global__ void gather_kernel(const float* __restrict__ ef,   // E x 8
                              const float* __restrict__ ea,   // E x 9
                              const int* __restrict__ eidx,   // 2 x E (senders at [0,E))
                              const float* __restrict__ h,    // N x 64
                              const float* __restrict__ Wc,   // 8 x 192
                              const int* __restrict__ start,
                              const int* __restrict__ counts,
                              const int* __restrict__ perm,
                              float* __restrict__ msg) {      // N x 576
    __shared__ float WcL[8 * WC_COLS];
    const int t = threadIdx.x, lane = t & 63, wv = t >> 6;
    for (int i = t; i < 8 * WC_COLS; i += 256) WcL[i] = Wc[i];
    __syncthreads();

    const int n = blockIdx.x * 4 + wv;
    if (n >= N_NODES) return;
    const int s0 = start[n], cnt = counts[n];

    float p0 = 0.f;
    float p1[3] = {0.f, 0.f, 0.f};
    float p2[5] = {0.f, 0.f, 0.f, 0.f, 0.f};

    for (int j = 0; j < cnt; ++j) {
        const int e = perm[s0 + j];
        const int snd = eidx[e];
        const float xs = h[(size_t)snd * 64 + lane];

        const float4* ef4 = reinterpret_cast<const float4*>(ef + (size_t)e * 8);
        const float4 fa = ef4[0], fb = ef4[1];
        float w0, w1, w2;
        {
            const float* fk = reinterpret_cast<const float*>(&fa);
            w0 = fk[0] * WcL[0 * WC_COLS + lane];
            w1 = fk[0] * WcL[0 * WC_COLS + 64 + lane];
            w2 = fk[0] * WcL[0 * WC_COLS + 128 + lane];
            #pragma unroll
            for (int k = 1; k < 4; ++k) {
                w0 += fk[k] * WcL[k * WC_COLS + lane];
                w1 += fk[k] * WcL[k * WC_COLS + 64 + lane];
                w2 += fk[k] * WcL[k * WC_COLS + 128 + lane];
            }
            const float* gk = reinterpret_cast<const float*>(&fb);
            #pragma unroll
            for (int k = 0; k < 4; ++k) {
                w0 += gk[k] * WcL[(k + 4) * WC_COLS + lane];
                w1 += gk[k] * WcL[(k + 4) * WC_COLS + 64 + lane];
                w2 += gk[k] * WcL[(k + 4) * WC_COLS + 128 + lane];
            }
        }
        const float* y = ea + (size_t)e * 9;   // wave-uniform
        const float a0 = xs * w0, a1 = xs * w1, a2 = xs * w2;
        p0    += a0 * y[0];
        p1[0] += a1 * y[1];
        p1[1] += a1 * y[2];
        p1[2] += a1 * y[3];
        p2[0] += a2 * y[4];
        p2[1] += a2 * y[5];
        p2[2] += a2 * y[6];
        p2[3] += a2 * y[7];
        p2[4] += a2 * y[8];
    }

    float* mrow = msg + (size_t)n * MSG_DIM;
    mrow[lane] = p0;
    #pragma unroll
    for (int m = 0; m < 3; ++m) mrow[64 + lane * 3 + m] = p1[m];
    #pragma unroll
    for (int m = 0; m < 5; ++m) mrow[256 + lane * 5 + m] = p2[m];
}

// ---------------------------------------------------------------------------
// Kernel 4: per-node W_msg transform, in place on the msg/out buffer.
// 16 nodes / block (4 iters x 4 waves), grid 1250. W_msg in LDS (48 KB);
// msg row streamed directly from global as aligned float4 broadcasts
// (each element read exactly once -> no LDS staging).
// u-step = 8: chunk sizes 8/24/40 floats, all 16B-aligned.
// ---------------------------------------------------------------------------
__global__ __launch_bounds__(256) void out_transform(
        const float* __restrict__ Wmsg,  // 3*64*64
        float* __restrict__ out) {       // N x 576 (in = msg, out in place)
    __shared__ float WL[3 * 64 * 64];
    const int t = threadIdx.x, lane = t & 63, wv = t >> 6;
    for (int i = t; i < 3 * 64 * 64; i += 256) WL[i] = Wmsg[i];
    __syncthreads();
    const float scale = 1.f / 128.f;  // 1/(sqrt(64)*16)

    #pragma unroll 1
    for (int it = 0; it < 4; ++it) {
        const int n = blockIdx.x * 16 + it * 4 + wv;
        if (n >= N_NODES) return;
        float* rowp = out + (size_t)n * MSG_DIM;

        float o[9] = {0.f, 0.f, 0.f, 0.f, 0.f, 0.f, 0.f, 0.f, 0.f};
        #pragma unroll 1
        for (int u8 = 0; u8 < 8; ++u8) {
            const int u0 = u8 * 8;
            float w0[8], w1[8], w2[8];
            #pragma unroll
            for (int j = 0; j < 8; ++j) {
                w0[j] = WL[(u0 + j) * 64 + lane];
                w1[j] = WL[4096 + (u0 + j) * 64 + lane];
                w2[j] = WL[8192 + (u0 + j) * 64 + lane];
            }
            float c0[8];
            {
                const float4* p = reinterpret_cast<const float4*>(rowp + u0);
                #pragma unroll
                for (int q = 0; q < 2; ++q) {
                    float4 v = p[q];
                    c0[q * 4 + 0] = v.x; c0[q * 4 + 1] = v.y;
                    c0[q * 4 + 2] = v.z; c0[q * 4 + 3] = v.w;
                }
            }
            float c1[24];
            {
                const float4* p = reinterpret_cast<const float4*>(rowp + 64 + u0 * 3);
                #pragma unroll
                for (int q = 0; q < 6; ++q) {
                    float4 v = p[q];
                    c1[q * 4 + 0] = v.x; c1[q * 4 + 1] = v.y;
                    c1[q * 4 + 2] = v.z; c1[q * 4 + 3] = v.w;
                }
            }
            float c2[40];
            {
                const float4* p = reinterpret_cast<const float4*>(rowp + 256 + u0 * 5);
                #pragma unroll
                for (int q = 0; q < 10; ++q) {
                    float4 v = p[q];
                    c2[q * 4 + 0] = v.x; c2[q * 4 + 1] = v.y;
                    c2[q * 4 + 2] = v.z; c2[q * 4 + 3] = v.w;
                }
            }
            #pragma unroll
            for (int j = 0; j < 8; ++j) {
                o[0] += c0[j] * w0[j];
                #pragma unroll
                for (int m = 0; m < 3; ++m) o[1 + m] += c1[j * 3 + m] * w1[j];
                #pragma unroll
                for (int m = 0; m < 5; ++m) o[4 + m] += c2[j * 5 + m] * w2[j];
            }
        }
        float* op = rowp + lane * 9;
        #pragma unroll
        for (int m = 0; m < 9; ++m) op[m] = o[m] * scale;
    }
}

// ---------------------------------------------------------------------------
// Kernel 5: sc[n,w] = sum_{u,v} h[n,u]*attrs[n,v]*W_skip[u,v,w] / sqrt(640)
// ---------------------------------------------------------------------------
__global__ void skip_kernel(const float* __restrict__ h,
                            const float* __restrict__ attrs,
                            const float* __restrict__ Wskip,  // 64*10*64
                            float* __restrict__ sc) {
    __shared__ float hl[32 * 64];
    __shared__ float al[32 * NATTR];
    const int t = threadIdx.x, lane = t & 63, wv = t >> 6;
    const int nb = blockIdx.x * 32;
    for (int i = t; i < 32 * 64; i += 256) hl[i] = h[(size_t)(nb + (i >> 6)) * 64 + (i & 63)];
    for (int i = t; i < 32 * NATTR; i += 256) al[i] = attrs[(size_t)(nb + i / NATTR) * NATTR + i % NATTR];
    __syncthreads();

    float acc[8] = {0.f, 0.f, 0.f, 0.f, 0.f, 0.f, 0.f, 0.f};
    for (int u = 0; u < 64; ++u) {
        #pragma unroll
        for (int v = 0; v < NATTR; ++v) {
            const float wk = Wskip[(u * NATTR + v) * 64 + lane];
            #pragma unroll
            for (int i = 0; i < 8; ++i) {
                const int nl = wv + 4 * i;
                acc[i] += hl[nl * 64 + u] * al[nl * NATTR + v] * wk;
            }
        }
    }
    const float scale = 0.03952847075210474f;  // 1/sqrt(640)
    #pragma unroll
    for (int i = 0; i < 8; ++i)
        sc[(size_t)(nb + wv + 4 * i) * 64 + lane] = acc[i] * scale;
}

// ---------------------------------------------------------------------------
extern "C" void kernel_launch(void* const* d_in, const int* in_sizes, int n_in,
                              void* d_out, int out_size, void* d_ws, size_t ws_size,
                              hipStream_t stream) {
    const float* node_attrs = (const float*)d_in[0];
    const float* node_feats = (const float*)d_in[1];
    const float* edge_attrs = (const float*)d_in[2];
    const float* edge_feats = (const float*)d_in[3];
    const int*   edge_index = (const int*)d_in[4];
    const float* W_lin1 = (const float*)d_in[5];
    const float* W_r0 = (const float*)d_in[6];
    const float* W_r1 = (const float*)d_in[7];
    const float* W_r2 = (const float*)d_in[8];
    const float* W_r3 = (const float*)d_in[9];
    const float* W_msg = (const float*)d_in[10];
    const float* W_skip = (const float*)d_in[11];

    float* out = (float*)d_out;                       // N x 576 (msg, transformed in place)
    float* sc  = out + (size_t)N_NODES * MSG_DIM;     // N x 64

    float* wsf = (float*)d_ws;
    float* Wc = wsf;                          // 1536 floats (pad to 2048)
    float* h  = wsf + 2048;                   // N*64
    int* wsi   = (int*)(wsf + 2048 + (size_t)N_NODES * 64);
    int* counts = wsi;                        // N
    int* start  = wsi + N_NODES;              // N
    int* cursor = wsi + 2 * N_NODES;          // N
    int* perm   = wsi + 3 * N_NODES;          // E

    combine_radial<<<1, 256, 0, stream>>>(W_r0, W_r1, W_r2, W_r3, Wc);
    node_linear<<<1250, 256, 0, stream>>>(node_feats, W_lin1, h);

    hipMemsetAsync(counts, 0, N_NODES * sizeof(int), stream);
    hist_kernel<<<(N_EDGES + 255) / 256, 256, 0, stream>>>(edge_index, counts);
    scan_kernel<<<1, 256, 0, stream>>>(counts, start, cursor);
    scatter_kernel<<<(N_EDGES + 255) / 256, 256, 0, stream>>>(edge_index, cursor, perm);

    gather_kernel<<<(N_NODES + 3) / 4, 256, 0, stream>>>(
        edge_feats, edge_attrs, edge_index, h, Wc, start, counts, perm, out);

    out_transform<<<1250, 256, 0, stream>>>(W_msg, out);
    skip_kernel<<<625, 256, 0, stream>>>(h, node_attrs, W_skip, sc);
}

// Round 4
// 379.595 us; speedup vs baseline: 6.7837x; 1.0355x over previous
//
#include <hip/hip_runtime.h>

#define N_NODES 20000
#define N_EDGES 320000
#define C 64
#define NATTR 10
#define MSG_DIM 576      // C*(1+3+5)
#define WC_COLS 192      // 3*C

// ---------------------------------------------------------------------------
// Kernel 1: collapse the (linear) radial MLP into Wc (8 x 192), one block.
// ---------------------------------------------------------------------------
__global__ void combine_radial(const float* __restrict__ Wr0,
                               const float* __restrict__ Wr1,
                               const float* __restrict__ Wr2,
                               const float* __restrict__ Wr3,
                               float* __restrict__ Wc) {
    __shared__ float T[8 * 64];
    __shared__ float T2[8 * 64];
    const int t = threadIdx.x;  // 256
    const float s0 = 0.35355339059327373f;  // 1/sqrt(8)
    const float s1 = 0.125f;                // 1/8

    for (int i = t; i < 8 * 64; i += 256) {
        int r = i >> 6, c = i & 63;
        float acc = 0.f;
        for (int k = 0; k < 64; ++k) acc += Wr0[r * 64 + k] * Wr1[k * 64 + c];
        T[i] = acc * (s0 * s1);
    }
    __syncthreads();
    for (int i = t; i < 8 * 64; i += 256) {
        int r = i >> 6, c = i & 63;
        float acc = 0.f;
        for (int k = 0; k < 64; ++k) acc += T[r * 64 + k] * Wr2[k * 64 + c];
        T2[i] = acc * s1;
    }
    __syncthreads();
    for (int i = t; i < 8 * WC_COLS; i += 256) {
        int r = i / WC_COLS, c = i % WC_COLS;
        float acc = 0.f;
        for (int k = 0; k < 64; ++k) acc += T2[r * 64 + k] * Wr3[k * WC_COLS + c];
        Wc[i] = acc * s1;
    }
}

// ---------------------------------------------------------------------------
// Kernel 2: h = node_feats @ (W_lin1 / 8).
// ---------------------------------------------------------------------------
__global__ void node_linear(const float* __restrict__ nf,
                            const float* __restrict__ W,
                            float* __restrict__ h) {
    __shared__ float Ws[64 * 64];
    __shared__ float row[4][64];
    const int t = threadIdx.x, lane = t & 63, wv = t >> 6;
    for (int i = t; i < 4096; i += 256) Ws[i] = W[i] * 0.125f;
    __syncthreads();
    const int base = blockIdx.x * 16;
    for (int it = 0; it < 4; ++it) {
        int n = base + it * 4 + wv;
        if (n >= N_NODES) break;
        row[wv][lane] = nf[(size_t)n * 64 + lane];
        float acc = 0.f;
        #pragma unroll
        for (int k = 0; k < 64; ++k) acc += row[wv][k] * Ws[k * 64 + lane];
        h[(size_t)n * 64 + lane] = acc;
    }
}

// ---------------------------------------------------------------------------
// Sort-by-receiver pipeline: histogram -> scan -> scatter (counting sort).
// ---------------------------------------------------------------------------
__global__ void hist_kernel(const int* __restrict__ eidx, int* __restrict__ counts) {
    const int e = blockIdx.x * 256 + threadIdx.x;
    if (e < N_EDGES) atomicAdd(&counts[eidx[N_EDGES + e]], 1);
}

#define SCAN_CHUNK 79   // ceil(20000/256) = 79
__global__ void scan_kernel(const int* __restrict__ counts,
                            int* __restrict__ start, int* __restrict__ cursor) {
    __shared__ int tot[256];
    __shared__ int pre[256];
    const int t = threadIdx.x;
    const int base = t * SCAN_CHUNK;
    int s = 0;
    for (int j = 0; j < SCAN_CHUNK; ++j) {
        int idx = base + j;
        if (idx < N_NODES) s += counts[idx];
    }
    tot[t] = s;
    __syncthreads();
    if (t == 0) {
        int a = 0;
        for (int i = 0; i < 256; ++i) { pre[i] = a; a += tot[i]; }
    }
    __syncthreads();
    int a = pre[t];
    for (int j = 0; j < SCAN_CHUNK; ++j) {
        int idx = base + j;
        if (idx < N_NODES) {
            start[idx] = a;
            cursor[idx] = a;
            a += counts[idx];
        }
    }
}

__global__ void scatter_kernel(const int* __restrict__ eidx,
                               int* __restrict__ cursor, int* __restrict__ perm) {
    const int e = blockIdx.x * 256 + threadIdx.x;
    if (e < N_EDGES) {
        const int r = eidx[N_EDGES + e];
        const int pos = atomicAdd(&cursor[r], 1);
        perm[pos] = e;
    }
}

// ---------------------------------------------------------------------------
// Kernel 3: gather — one wave per node; 4-edge batched loads to maximize
// memory-level parallelism (Little's law), accumulate in registers,
// write the 576-float msg row once.
// ---------------------------------------------------------------------------
__global__ __launch_bounds__(256) void gather_kernel(
                              const float* __restrict__ ef,   // E x 8
                              const float* __restrict__ ea,   // E x 9
                              const int* __restrict__ eidx,   // 2 x E (senders at [0,E))
                              const float* __restrict__ h,    // N x 64
                              const float* __restrict__ Wc,   // 8 x 192
                              const int* __restrict__ start,
                              const int* __restrict__ counts,
                              const int* __restrict__ perm,
                              float* __restrict__ msg) {      // N x 576
    __shared__ float WcL[8 * WC_COLS];
    const int t = threadIdx.x, lane = t & 63, wv = t >> 6;
    for (int i = t; i < 8 * WC_COLS; i += 256) WcL[i] = Wc[i];
    __syncthreads();

    const int n = blockIdx.x * 4 + wv;
    if (n >= N_NODES) return;
    const int s0 = start[n], cnt = counts[n];

    float p0 = 0.f;
    float p1[3] = {0.f, 0.f, 0.f};
    float p2[5] = {0.f, 0.f, 0.f, 0.f, 0.f};

    int j = 0;
    for (; j + 4 <= cnt; j += 4) {
        // round 1: 4 independent perm loads
        int e[4];
        #pragma unroll
        for (int b = 0; b < 4; ++b) e[b] = perm[s0 + j + b];
        // round 2: 4 independent sender loads
        int snd[4];
        #pragma unroll
        for (int b = 0; b < 4; ++b) snd[b] = eidx[e[b]];
        // round 3: all payload loads issued together (4 x (2*float4 + 9 + 1))
        float4 fa[4], fb[4];
        float xs[4];
        float y[4][9];
        #pragma unroll
        for (int b = 0; b < 4; ++b) {
            const float4* ef4 = reinterpret_cast<const float4*>(ef + (size_t)e[b] * 8);
            fa[b] = ef4[0];
            fb[b] = ef4[1];
            xs[b] = h[(size_t)snd[b] * 64 + lane];
            const float* yp = ea + (size_t)e[b] * 9;
            #pragma unroll
            for (int q = 0; q < 9; ++q) y[b][q] = yp[q];
        }
        // compute
        #pragma unroll
        for (int b = 0; b < 4; ++b) {
            const float* fk = reinterpret_cast<const float*>(&fa[b]);
            const float* gk = reinterpret_cast<const float*>(&fb[b]);
            float w0 = fk[0] * WcL[0 * WC_COLS + lane];
            float w1 = fk[0] * WcL[0 * WC_COLS + 64 + lane];
            float w2 = fk[0] * WcL[0 * WC_COLS + 128 + lane];
            #pragma unroll
            for (int k = 1; k < 4; ++k) {
                w0 += fk[k] * WcL[k * WC_COLS + lane];
                w1 += fk[k] * WcL[k * WC_COLS + 64 + lane];
                w2 += fk[k] * WcL[k * WC_COLS + 128 + lane];
            }
            #pragma unroll
            for (int k = 0; k < 4; ++k) {
                w0 += gk[k] * WcL[(k + 4) * WC_COLS + lane];
                w1 += gk[k] * WcL[(k + 4) * WC_COLS + 64 + lane];
                w2 += gk[k] * WcL[(k + 4) * WC_COLS + 128 + lane];
            }
            const float a0 = xs[b] * w0, a1 = xs[b] * w1, a2 = xs[b] * w2;
            p0    += a0 * y[b][0];
            p1[0] += a1 * y[b][1];
            p1[1] += a1 * y[b][2];
            p1[2] += a1 * y[b][3];
            p2[0] += a2 * y[b][4];
            p2[1] += a2 * y[b][5];
            p2[2] += a2 * y[b][6];
            p2[3] += a2 * y[b][7];
            p2[4] += a2 * y[b][8];
        }
    }
    // remainder
    for (; j < cnt; ++j) {
        const int e = perm[s0 + j];
        const int snd = eidx[e];
        const float xs = h[(size_t)snd * 64 + lane];
        const float4* ef4 = reinterpret_cast<const float4*>(ef + (size_t)e * 8);
        const float4 fa = ef4[0], fb = ef4[1];
        const float* fk = reinterpret_cast<const float*>(&fa);
        const float* gk = reinterpret_cast<const float*>(&fb);
        float w0 = fk[0] * WcL[0 * WC_COLS + lane];
        float w1 = fk[0] * WcL[0 * WC_COLS + 64 + lane];
        float w2 = fk[0] * WcL[0 * WC_COLS + 128 + lane];
        #pragma unroll
        for (int k = 1; k < 4; ++k) {
            w0 += fk[k] * WcL[k * WC_COLS + lane];
            w1 += fk[k] * WcL[k * WC_COLS + 64 + lane];
            w2 += fk[k] * WcL[k * WC_COLS + 128 + lane];
        }
        #pragma unroll
        for (int k = 0; k < 4; ++k) {
            w0 += gk[k] * WcL[(k + 4) * WC_COLS + lane];
            w1 += gk[k] * WcL[(k + 4) * WC_COLS + 64 + lane];
            w2 += gk[k] * WcL[(k + 4) * WC_COLS + 128 + lane];
        }
        const float* y = ea + (size_t)e * 9;
        const float a0 = xs * w0, a1 = xs * w1, a2 = xs * w2;
        p0    += a0 * y[0];
        p1[0] += a1 * y[1];
        p1[1] += a1 * y[2];
        p1[2] += a1 * y[3];
        p2[0] += a2 * y[4];
        p2[1] += a2 * y[5];
        p2[2] += a2 * y[6];
        p2[3] += a2 * y[7];
        p2[4] += a2 * y[8];
    }

    float* mrow = msg + (size_t)n * MSG_DIM;
    mrow[lane] = p0;
    #pragma unroll
    for (int m = 0; m < 3; ++m) mrow[64 + lane * 3 + m] = p1[m];
    #pragma unroll
    for (int m = 0; m < 5; ++m) mrow[256 + lane * 5 + m] = p2[m];
}

// ---------------------------------------------------------------------------
// Kernel 4: per-node W_msg transform, in place on the msg/out buffer.
// ---------------------------------------------------------------------------
__global__ __launch_bounds__(256) void out_transform(
        const float* __restrict__ Wmsg,  // 3*64*64
        float* __restrict__ out) {       // N x 576 (in = msg, out in place)
    __shared__ float WL[3 * 64 * 64];
    const int t = threadIdx.x, lane = t & 63, wv = t >> 6;
    for (int i = t; i < 3 * 64 * 64; i += 256) WL[i] = Wmsg[i];
    __syncthreads();
    const float scale = 1.f / 128.f;  // 1/(sqrt(64)*16)

    #pragma unroll 1
    for (int it = 0; it < 4; ++it) {
        const int n = blockIdx.x * 16 + it * 4 + wv;
        if (n >= N_NODES) return;
        float* rowp = out + (size_t)n * MSG_DIM;

        float o[9] = {0.f, 0.f, 0.f, 0.f, 0.f, 0.f, 0.f, 0.f, 0.f};
        #pragma unroll 1
        for (int u8 = 0; u8 < 8; ++u8) {
            const int u0 = u8 * 8;
            float w0[8], w1[8], w2[8];
            #pragma unroll
            for (int j = 0; j < 8; ++j) {
                w0[j] = WL[(u0 + j) * 64 + lane];
                w1[j] = WL[4096 + (u0 + j) * 64 + lane];
                w2[j] = WL[8192 + (u0 + j) * 64 + lane];
            }
            float c0[8];
            {
                const float4* p = reinterpret_cast<const float4*>(rowp + u0);
                #pragma unroll
                for (int q = 0; q < 2; ++q) {
                    float4 v = p[q];
                    c0[q * 4 + 0] = v.x; c0[q * 4 + 1] = v.y;
                    c0[q * 4 + 2] = v.z; c0[q * 4 + 3] = v.w;
                }
            }
            float c1[24];
            {
                const float4* p = reinterpret_cast<const float4*>(rowp + 64 + u0 * 3);
                #pragma unroll
                for (int q = 0; q < 6; ++q) {
                    float4 v = p[q];
                    c1[q * 4 + 0] = v.x; c1[q * 4 + 1] = v.y;
                    c1[q * 4 + 2] = v.z; c1[q * 4 + 3] = v.w;
                }
            }
            float c2[40];
            {
                const float4* p = reinterpret_cast<const float4*>(rowp + 256 + u0 * 5);
                #pragma unroll
                for (int q = 0; q < 10; ++q) {
                    float4 v = p[q];
                    c2[q * 4 + 0] = v.x; c2[q * 4 + 1] = v.y;
                    c2[q * 4 + 2] = v.z; c2[q * 4 + 3] = v.w;
                }
            }
            #pragma unroll
            for (int j = 0; j < 8; ++j) {
                o[0] += c0[j] * w0[j];
                #pragma unroll
                for (int m = 0; m < 3; ++m) o[1 + m] += c1[j * 3 + m] * w1[j];
                #pragma unroll
                for (int m = 0; m < 5; ++m) o[4 + m] += c2[j * 5 + m] * w2[j];
            }
        }
        float* op = rowp + lane * 9;
        #pragma unroll
        for (int m = 0; m < 9; ++m) op[m] = o[m] * scale;
    }
}

// ---------------------------------------------------------------------------
// Kernel 5: sc[n,w] = sum_{u,v} h[n,u]*attrs[n,v]*W_skip[u,v,w] / sqrt(640)
// Restructured: attrs in registers, LDS float4 h reads, h-multiply factored
// out of the v-loop -> ~5.6K VALU instrs/wave instead of ~10K LDS reads.
// ---------------------------------------------------------------------------
__global__ __launch_bounds__(256) void skip_kernel(
                            const float* __restrict__ h,
                            const float* __restrict__ attrs,
                            const float* __restrict__ Wskip,  // 64*10*64
                            float* __restrict__ sc) {
    __shared__ float hl[32 * 64];
    const int t = threadIdx.x, lane = t & 63, wv = t >> 6;
    const int nb = blockIdx.x * 32;
    for (int i = t; i < 32 * 64; i += 256) hl[i] = h[(size_t)(nb + (i >> 6)) * 64 + (i & 63)];
    __syncthreads();

    // attrs for this thread's 8 nodes, in registers (broadcast loads)
    float alr[8][NATTR];
    #pragma unroll
    for (int i = 0; i < 8; ++i) {
        const float* ap = attrs + (size_t)(nb + wv + 4 * i) * NATTR;
        #pragma unroll
        for (int v = 0; v < NATTR; ++v) alr[i][v] = ap[v];
    }

    float acc[8] = {0.f, 0.f, 0.f, 0.f, 0.f, 0.f, 0.f, 0.f};
    #pragma unroll 1
    for (int u4 = 0; u4 < 16; ++u4) {
        const int u0 = u4 * 4;
        float4 hu[8];
        #pragma unroll
        for (int i = 0; i < 8; ++i)
            hu[i] = *reinterpret_cast<const float4*>(&hl[(wv + 4 * i) * 64 + u0]);
        #pragma unroll
        for (int uu = 0; uu < 4; ++uu) {
            float tmp[8] = {0.f, 0.f, 0.f, 0.f, 0.f, 0.f, 0.f, 0.f};
            #pragma unroll
            for (int v = 0; v < NATTR; ++v) {
                const float wk = Wskip[((u0 + uu) * NATTR + v) * 64 + lane];
                #pragma unroll
                for (int i = 0; i < 8; ++i) tmp[i] += alr[i][v] * wk;
            }
            #pragma unroll
            for (int i = 0; i < 8; ++i) {
                const float huv = (uu == 0) ? hu[i].x : (uu == 1) ? hu[i].y
                                 : (uu == 2) ? hu[i].z : hu[i].w;
                acc[i] += huv * tmp[i];
            }
        }
    }
    const float scale = 0.03952847075210474f;  // 1/sqrt(640)
    #pragma unroll
    for (int i = 0; i < 8; ++i)
        sc[(size_t)(nb + wv + 4 * i) * 64 + lane] = acc[i] * scale;
}

// ---------------------------------------------------------------------------
extern "C" void kernel_launch(void* const* d_in, const int* in_sizes, int n_in,
                              void* d_out, int out_size, void* d_ws, size_t ws_size,
                              hipStream_t stream) {
    const float* node_attrs = (const float*)d_in[0];
    const float* node_feats = (const float*)d_in[1];
    const float* edge_attrs = (const float*)d_in[2];
    const float* edge_feats = (const float*)d_in[3];
    const int*   edge_index = (const int*)d_in[4];
    const float* W_lin1 = (const float*)d_in[5];
    const float* W_r0 = (const float*)d_in[6];
    const float* W_r1 = (const float*)d_in[7];
    const float* W_r2 = (const float*)d_in[8];
    const float* W_r3 = (const float*)d_in[9];
    const float* W_msg = (const float*)d_in[10];
    const float* W_skip = (const float*)d_in[11];

    float* out = (float*)d_out;                       // N x 576 (msg, transformed in place)
    float* sc  = out + (size_t)N_NODES * MSG_DIM;     // N x 64

    float* wsf = (float*)d_ws;
    float* Wc = wsf;                          // 1536 floats (pad to 2048)
    float* h  = wsf + 2048;                   // N*64
    int* wsi   = (int*)(wsf + 2048 + (size_t)N_NODES * 64);
    int* counts = wsi;                        // N
    int* start  = wsi + N_NODES;              // N
    int* cursor = wsi + 2 * N_NODES;          // N
    int* perm   = wsi + 3 * N_NODES;          // E

    combine_radial<<<1, 256, 0, stream>>>(W_r0, W_r1, W_r2, W_r3, Wc);
    node_linear<<<1250, 256, 0, stream>>>(node_feats, W_lin1, h);

    hipMemsetAsync(counts, 0, N_NODES * sizeof(int), stream);
    hist_kernel<<<(N_EDGES + 255) / 256, 256, 0, stream>>>(edge_index, counts);
    scan_kernel<<<1, 256, 0, stream>>>(counts, start, cursor);
    scatter_kernel<<<(N_EDGES + 255) / 256, 256, 0, stream>>>(edge_index, cursor, perm);

    gather_kernel<<<(N_NODES + 3) / 4, 256, 0, stream>>>(
        edge_feats, edge_attrs, edge_index, h, Wc, start, counts, perm, out);

    out_transform<<<1250, 256, 0, stream>>>(W_msg, out);
    skip_kernel<<<625, 256, 0, stream>>>(h, node_attrs, W_skip, sc);
}

// Round 5
// 363.398 us; speedup vs baseline: 7.0860x; 1.0446x over previous
//
#include <hip/hip_runtime.h>

#define N_NODES 20000
#define N_EDGES 320000
#define C 64
#define NATTR 10
#define MSG_DIM 576      // C*(1+3+5)
#define WC_COLS 192      // 3*C

// ---------------------------------------------------------------------------
// Kernel 1: collapse the (linear) radial MLP into Wc (8 x 192), one block.
// ---------------------------------------------------------------------------
__global__ void combine_radial(const float* __restrict__ Wr0,
                               const float* __restrict__ Wr1,
                               const float* __restrict__ Wr2,
                               const float* __restrict__ Wr3,
                               float* __restrict__ Wc) {
    __shared__ float T[8 * 64];
    __shared__ float T2[8 * 64];
    const int t = threadIdx.x;  // 256
    const float s0 = 0.35355339059327373f;  // 1/sqrt(8)
    const float s1 = 0.125f;                // 1/8

    for (int i = t; i < 8 * 64; i += 256) {
        int r = i >> 6, c = i & 63;
        float acc = 0.f;
        for (int k = 0; k < 64; ++k) acc += Wr0[r * 64 + k] * Wr1[k * 64 + c];
        T[i] = acc * (s0 * s1);
    }
    __syncthreads();
    for (int i = t; i < 8 * 64; i += 256) {
        int r = i >> 6, c = i & 63;
        float acc = 0.f;
        for (int k = 0; k < 64; ++k) acc += T[r * 64 + k] * Wr2[k * 64 + c];
        T2[i] = acc * s1;
    }
    __syncthreads();
    for (int i = t; i < 8 * WC_COLS; i += 256) {
        int r = i / WC_COLS, c = i % WC_COLS;
        float acc = 0.f;
        for (int k = 0; k < 64; ++k) acc += T2[r * 64 + k] * Wr3[k * WC_COLS + c];
        Wc[i] = acc * s1;
    }
}

// ---------------------------------------------------------------------------
// Kernel 2: h = node_feats @ (W_lin1 / 8).
// ---------------------------------------------------------------------------
__global__ void node_linear(const float* __restrict__ nf,
                            const float* __restrict__ W,
                            float* __restrict__ h) {
    __shared__ float Ws[64 * 64];
    __shared__ float row[4][64];
    const int t = threadIdx.x, lane = t & 63, wv = t >> 6;
    for (int i = t; i < 4096; i += 256) Ws[i] = W[i] * 0.125f;
    __syncthreads();
    const int base = blockIdx.x * 16;
    for (int it = 0; it < 4; ++it) {
        int n = base + it * 4 + wv;
        if (n >= N_NODES) break;
        row[wv][lane] = nf[(size_t)n * 64 + lane];
        float acc = 0.f;
        #pragma unroll
        for (int k = 0; k < 64; ++k) acc += row[wv][k] * Ws[k * 64 + lane];
        h[(size_t)n * 64 + lane] = acc;
    }
}

// ---------------------------------------------------------------------------
// Sort pipeline: histogram -> scan -> scatter_build (counting sort that
// MATERIALIZES sorted edge records: snd_s, ef_s (8f), ea_s (12f padded)).
// ---------------------------------------------------------------------------
__global__ void hist_kernel(const int* __restrict__ eidx, int* __restrict__ counts) {
    const int e = blockIdx.x * 256 + threadIdx.x;
    if (e < N_EDGES) atomicAdd(&counts[eidx[N_EDGES + e]], 1);
}

#define SCAN_CHUNK 79   // ceil(20000/256) = 79
__global__ void scan_kernel(const int* __restrict__ counts,
                            int* __restrict__ start, int* __restrict__ cursor) {
    __shared__ int tot[256];
    __shared__ int pre[256];
    const int t = threadIdx.x;
    const int base = t * SCAN_CHUNK;
    int s = 0;
    for (int j = 0; j < SCAN_CHUNK; ++j) {
        int idx = base + j;
        if (idx < N_NODES) s += counts[idx];
    }
    tot[t] = s;
    __syncthreads();
    if (t == 0) {
        int a = 0;
        for (int i = 0; i < 256; ++i) { pre[i] = a; a += tot[i]; }
    }
    __syncthreads();
    int a = pre[t];
    for (int j = 0; j < SCAN_CHUNK; ++j) {
        int idx = base + j;
        if (idx < N_NODES) {
            start[idx] = a;
            cursor[idx] = a;
            a += counts[idx];
        }
    }
}

__global__ void scatter_build(const int* __restrict__ eidx,
                              const float* __restrict__ ef,
                              const float* __restrict__ ea,
                              int* __restrict__ cursor,
                              int* __restrict__ snd_s,
                              float* __restrict__ ef_s,
                              float* __restrict__ ea_s) {
    const int e = blockIdx.x * 256 + threadIdx.x;
    if (e >= N_EDGES) return;
    const int r = eidx[N_EDGES + e];
    const int pos = atomicAdd(&cursor[r], 1);
    snd_s[pos] = eidx[e];
    const float4* s4 = reinterpret_cast<const float4*>(ef + (size_t)e * 8);
    float4* d4 = reinterpret_cast<float4*>(ef_s + (size_t)pos * 8);
    d4[0] = s4[0];
    d4[1] = s4[1];
    const float* y = ea + (size_t)e * 9;
    float4* o4 = reinterpret_cast<float4*>(ea_s + (size_t)pos * 12);
    o4[0] = make_float4(y[0], y[1], y[2], y[3]);
    o4[1] = make_float4(y[4], y[5], y[6], y[7]);
    o4[2] = make_float4(y[8], 0.f, 0.f, 0.f);
}

// legacy scatter (fallback when ws too small for records)
__global__ void scatter_kernel(const int* __restrict__ eidx,
                               int* __restrict__ cursor, int* __restrict__ perm) {
    const int e = blockIdx.x * 256 + threadIdx.x;
    if (e < N_EDGES) {
        const int r = eidx[N_EDGES + e];
        const int pos = atomicAdd(&cursor[r], 1);
        perm[pos] = e;
    }
}

// ---------------------------------------------------------------------------
// Kernel 3: gather from SORTED records — one wave per node. All record reads
// are sequential (no indirection); only h[snd] is a (L2-resident) gather.
// ---------------------------------------------------------------------------
__global__ __launch_bounds__(256) void gather_sorted(
                              const float* __restrict__ ef_s,  // E x 8 sorted
                              const float* __restrict__ ea_s,  // E x 12 sorted
                              const int* __restrict__ snd_s,   // E sorted
                              const float* __restrict__ h,     // N x 64
                              const float* __restrict__ Wc,    // 8 x 192
                              const int* __restrict__ start,
                              const int* __restrict__ counts,
                              float* __restrict__ msg) {       // N x 576
    __shared__ float WcL[8 * WC_COLS];
    const int t = threadIdx.x, lane = t & 63, wv = t >> 6;
    for (int i = t; i < 8 * WC_COLS; i += 256) WcL[i] = Wc[i];
    __syncthreads();

    const int n = blockIdx.x * 4 + wv;
    if (n >= N_NODES) return;
    const int s0 = start[n], cnt = counts[n];

    float p0 = 0.f;
    float p1[3] = {0.f, 0.f, 0.f};
    float p2[5] = {0.f, 0.f, 0.f, 0.f, 0.f};

    int j = 0;
    for (; j + 4 <= cnt; j += 4) {
        const size_t r0 = (size_t)(s0 + j);
        // senders first so the dependent h loads issue early
        int snd[4];
        #pragma unroll
        for (int b = 0; b < 4; ++b) snd[b] = snd_s[r0 + b];
        float xs[4];
        #pragma unroll
        for (int b = 0; b < 4; ++b) xs[b] = h[(size_t)snd[b] * 64 + lane];
        // sequential record loads (independent, streaming)
        float4 fa[4], fb[4];
        #pragma unroll
        for (int b = 0; b < 4; ++b) {
            const float4* p = reinterpret_cast<const float4*>(ef_s + (r0 + b) * 8);
            fa[b] = p[0];
            fb[b] = p[1];
        }
        float4 ya[4], yb[4], yc[4];
        #pragma unroll
        for (int b = 0; b < 4; ++b) {
            const float4* p = reinterpret_cast<const float4*>(ea_s + (r0 + b) * 12);
            ya[b] = p[0];
            yb[b] = p[1];
            yc[b] = p[2];
        }
        #pragma unroll
        for (int b = 0; b < 4; ++b) {
            const float* fk = reinterpret_cast<const float*>(&fa[b]);
            const float* gk = reinterpret_cast<const float*>(&fb[b]);
            float w0 = fk[0] * WcL[0 * WC_COLS + lane];
            float w1 = fk[0] * WcL[0 * WC_COLS + 64 + lane];
            float w2 = fk[0] * WcL[0 * WC_COLS + 128 + lane];
            #pragma unroll
            for (int k = 1; k < 4; ++k) {
                w0 += fk[k] * WcL[k * WC_COLS + lane];
                w1 += fk[k] * WcL[k * WC_COLS + 64 + lane];
                w2 += fk[k] * WcL[k * WC_COLS + 128 + lane];
            }
            #pragma unroll
            for (int k = 0; k < 4; ++k) {
                w0 += gk[k] * WcL[(k + 4) * WC_COLS + lane];
                w1 += gk[k] * WcL[(k + 4) * WC_COLS + 64 + lane];
                w2 += gk[k] * WcL[(k + 4) * WC_COLS + 128 + lane];
            }
            const float a0 = xs[b] * w0, a1 = xs[b] * w1, a2 = xs[b] * w2;
            p0    += a0 * ya[b].x;
            p1[0] += a1 * ya[b].y;
            p1[1] += a1 * ya[b].z;
            p1[2] += a1 * ya[b].w;
            p2[0] += a2 * yb[b].x;
            p2[1] += a2 * yb[b].y;
            p2[2] += a2 * yb[b].z;
            p2[3] += a2 * yb[b].w;
            p2[4] += a2 * yc[b].x;
        }
    }
    for (; j < cnt; ++j) {
        const size_t r0 = (size_t)(s0 + j);
        const int snd = snd_s[r0];
        const float xs = h[(size_t)snd * 64 + lane];
        const float4* pf = reinterpret_cast<const float4*>(ef_s + r0 * 8);
        const float4 fa = pf[0], fb = pf[1];
        const float4* py = reinterpret_cast<const float4*>(ea_s + r0 * 12);
        const float4 ya = py[0], yb = py[1], yc = py[2];
        const float* fk = reinterpret_cast<const float*>(&fa);
        const float* gk = reinterpret_cast<const float*>(&fb);
        float w0 = fk[0] * WcL[0 * WC_COLS + lane];
        float w1 = fk[0] * WcL[0 * WC_COLS + 64 + lane];
        float w2 = fk[0] * WcL[0 * WC_COLS + 128 + lane];
        #pragma unroll
        for (int k = 1; k < 4; ++k) {
            w0 += fk[k] * WcL[k * WC_COLS + lane];
            w1 += fk[k] * WcL[k * WC_COLS + 64 + lane];
            w2 += fk[k] * WcL[k * WC_COLS + 128 + lane];
        }
        #pragma unroll
        for (int k = 0; k < 4; ++k) {
            w0 += gk[k] * WcL[(k + 4) * WC_COLS + lane];
            w1 += gk[k] * WcL[(k + 4) * WC_COLS + 64 + lane];
            w2 += gk[k] * WcL[(k + 4) * WC_COLS + 128 + lane];
        }
        const float a0 = xs * w0, a1 = xs * w1, a2 = xs * w2;
        p0    += a0 * ya.x;
        p1[0] += a1 * ya.y;
        p1[1] += a1 * ya.z;
        p1[2] += a1 * ya.w;
        p2[0] += a2 * yb.x;
        p2[1] += a2 * yb.y;
        p2[2] += a2 * yb.z;
        p2[3] += a2 * yb.w;
        p2[4] += a2 * yc.x;
    }

    float* mrow = msg + (size_t)n * MSG_DIM;
    mrow[lane] = p0;
    #pragma unroll
    for (int m = 0; m < 3; ++m) mrow[64 + lane * 3 + m] = p1[m];
    #pragma unroll
    for (int m = 0; m < 5; ++m) mrow[256 + lane * 5 + m] = p2[m];
}

// legacy perm-based gather (fallback)
__global__ __launch_bounds__(256) void gather_perm(
                              const float* __restrict__ ef,
                              const float* __restrict__ ea,
                              const int* __restrict__ eidx,
                              const float* __restrict__ h,
                              const float* __restrict__ Wc,
                              const int* __restrict__ start,
                              const int* __restrict__ counts,
                              const int* __restrict__ perm,
                              float* __restrict__ msg) {
    __shared__ float WcL[8 * WC_COLS];
    const int t = threadIdx.x, lane = t & 63, wv = t >> 6;
    for (int i = t; i < 8 * WC_COLS; i += 256) WcL[i] = Wc[i];
    __syncthreads();
    const int n = blockIdx.x * 4 + wv;
    if (n >= N_NODES) return;
    const int s0 = start[n], cnt = counts[n];
    float p0 = 0.f;
    float p1[3] = {0.f, 0.f, 0.f};
    float p2[5] = {0.f, 0.f, 0.f, 0.f, 0.f};
    for (int j = 0; j < cnt; ++j) {
        const int e = perm[s0 + j];
        const int snd = eidx[e];
        const float xs = h[(size_t)snd * 64 + lane];
        const float4* ef4 = reinterpret_cast<const float4*>(ef + (size_t)e * 8);
        const float4 fa = ef4[0], fb = ef4[1];
        const float* fk = reinterpret_cast<const float*>(&fa);
        const float* gk = reinterpret_cast<const float*>(&fb);
        float w0 = fk[0] * WcL[0 * WC_COLS + lane];
        float w1 = fk[0] * WcL[0 * WC_COLS + 64 + lane];
        float w2 = fk[0] * WcL[0 * WC_COLS + 128 + lane];
        #pragma unroll
        for (int k = 1; k < 4; ++k) {
            w0 += fk[k] * WcL[k * WC_COLS + lane];
            w1 += fk[k] * WcL[k * WC_COLS + 64 + lane];
            w2 += fk[k] * WcL[k * WC_COLS + 128 + lane];
        }
        #pragma unroll
        for (int k = 0; k < 4; ++k) {
            w0 += gk[k] * WcL[(k + 4) * WC_COLS + lane];
            w1 += gk[k] * WcL[(k + 4) * WC_COLS + 64 + lane];
            w2 += gk[k] * WcL[(k + 4) * WC_COLS + 128 + lane];
        }
        const float* y = ea + (size_t)e * 9;
        const float a0 = xs * w0, a1 = xs * w1, a2 = xs * w2;
        p0    += a0 * y[0];
        p1[0] += a1 * y[1];
        p1[1] += a1 * y[2];
        p1[2] += a1 * y[3];
        p2[0] += a2 * y[4];
        p2[1] += a2 * y[5];
        p2[2] += a2 * y[6];
        p2[3] += a2 * y[7];
        p2[4] += a2 * y[8];
    }
    float* mrow = msg + (size_t)n * MSG_DIM;
    mrow[lane] = p0;
    #pragma unroll
    for (int m = 0; m < 3; ++m) mrow[64 + lane * 3 + m] = p1[m];
    #pragma unroll
    for (int m = 0; m < 5; ++m) mrow[256 + lane * 5 + m] = p2[m];
}

// ---------------------------------------------------------------------------
// Kernel 4: per-node W_msg transform, in place on the msg/out buffer.
// ---------------------------------------------------------------------------
__global__ __launch_bounds__(256) void out_transform(
        const float* __restrict__ Wmsg,  // 3*64*64
        float* __restrict__ out) {       // N x 576 (in = msg, out in place)
    __shared__ float WL[3 * 64 * 64];
    const int t = threadIdx.x, lane = t & 63, wv = t >> 6;
    for (int i = t; i < 3 * 64 * 64; i += 256) WL[i] = Wmsg[i];
    __syncthreads();
    const float scale = 1.f / 128.f;  // 1/(sqrt(64)*16)

    #pragma unroll 1
    for (int it = 0; it < 4; ++it) {
        const int n = blockIdx.x * 16 + it * 4 + wv;
        if (n >= N_NODES) return;
        float* rowp = out + (size_t)n * MSG_DIM;

        float o[9] = {0.f, 0.f, 0.f, 0.f, 0.f, 0.f, 0.f, 0.f, 0.f};
        #pragma unroll 1
        for (int u8 = 0; u8 < 8; ++u8) {
            const int u0 = u8 * 8;
            float w0[8], w1[8], w2[8];
            #pragma unroll
            for (int j = 0; j < 8; ++j) {
                w0[j] = WL[(u0 + j) * 64 + lane];
                w1[j] = WL[4096 + (u0 + j) * 64 + lane];
                w2[j] = WL[8192 + (u0 + j) * 64 + lane];
            }
            float c0[8];
            {
                const float4* p = reinterpret_cast<const float4*>(rowp + u0);
                #pragma unroll
                for (int q = 0; q < 2; ++q) {
                    float4 v = p[q];
                    c0[q * 4 + 0] = v.x; c0[q * 4 + 1] = v.y;
                    c0[q * 4 + 2] = v.z; c0[q * 4 + 3] = v.w;
                }
            }
            float c1[24];
            {
                const float4* p = reinterpret_cast<const float4*>(rowp + 64 + u0 * 3);
                #pragma unroll
                for (int q = 0; q < 6; ++q) {
                    float4 v = p[q];
                    c1[q * 4 + 0] = v.x; c1[q * 4 + 1] = v.y;
                    c1[q * 4 + 2] = v.z; c1[q * 4 + 3] = v.w;
                }
            }
            float c2[40];
            {
                const float4* p = reinterpret_cast<const float4*>(rowp + 256 + u0 * 5);
                #pragma unroll
                for (int q = 0; q < 10; ++q) {
                    float4 v = p[q];
                    c2[q * 4 + 0] = v.x; c2[q * 4 + 1] = v.y;
                    c2[q * 4 + 2] = v.z; c2[q * 4 + 3] = v.w;
                }
            }
            #pragma unroll
            for (int j = 0; j < 8; ++j) {
                o[0] += c0[j] * w0[j];
                #pragma unroll
                for (int m = 0; m < 3; ++m) o[1 + m] += c1[j * 3 + m] * w1[j];
                #pragma unroll
                for (int m = 0; m < 5; ++m) o[4 + m] += c2[j * 5 + m] * w2[j];
            }
        }
        float* op = rowp + lane * 9;
        #pragma unroll
        for (int m = 0; m < 9; ++m) op[m] = o[m] * scale;
    }
}

// ---------------------------------------------------------------------------
// Kernel 5: sc[n,w] = sum_{u,v} h[n,u]*attrs[n,v]*W_skip[u,v,w] / sqrt(640)
// ---------------------------------------------------------------------------
__global__ __launch_bounds__(256) void skip_kernel(
                            const float* __restrict__ h,
                            const float* __restrict__ attrs,
                            const float* __restrict__ Wskip,  // 64*10*64
                            float* __restrict__ sc) {
    __shared__ float hl[32 * 64];
    const int t = threadIdx.x, lane = t & 63, wv = t >> 6;
    const int nb = blockIdx.x * 32;
    for (int i = t; i < 32 * 64; i += 256) hl[i] = h[(size_t)(nb + (i >> 6)) * 64 + (i & 63)];
    __syncthreads();

    float alr[8][NATTR];
    #pragma unroll
    for (int i = 0; i < 8; ++i) {
        const float* ap = attrs + (size_t)(nb + wv + 4 * i) * NATTR;
        #pragma unroll
        for (int v = 0; v < NATTR; ++v) alr[i][v] = ap[v];
    }

    float acc[8] = {0.f, 0.f, 0.f, 0.f, 0.f, 0.f, 0.f, 0.f};
    #pragma unroll 1
    for (int u4 = 0; u4 < 16; ++u4) {
        const int u0 = u4 * 4;
        float4 hu[8];
        #pragma unroll
        for (int i = 0; i < 8; ++i)
            hu[i] = *reinterpret_cast<const float4*>(&hl[(wv + 4 * i) * 64 + u0]);
        #pragma unroll
        for (int uu = 0; uu < 4; ++uu) {
            float tmp[8] = {0.f, 0.f, 0.f, 0.f, 0.f, 0.f, 0.f, 0.f};
            #pragma unroll
            for (int v = 0; v < NATTR; ++v) {
                const float wk = Wskip[((u0 + uu) * NATTR + v) * 64 + lane];
                #pragma unroll
                for (int i = 0; i < 8; ++i) tmp[i] += alr[i][v] * wk;
            }
            #pragma unroll
            for (int i = 0; i < 8; ++i) {
                const float huv = (uu == 0) ? hu[i].x : (uu == 1) ? hu[i].y
                                 : (uu == 2) ? hu[i].z : hu[i].w;
                acc[i] += huv * tmp[i];
            }
        }
    }
    const float scale = 0.03952847075210474f;  // 1/sqrt(640)
    #pragma unroll
    for (int i = 0; i < 8; ++i)
        sc[(size_t)(nb + wv + 4 * i) * 64 + lane] = acc[i] * scale;
}

// ---------------------------------------------------------------------------
extern "C" void kernel_launch(void* const* d_in, const int* in_sizes, int n_in,
                              void* d_out, int out_size, void* d_ws, size_t ws_size,
                              hipStream_t stream) {
    const float* node_attrs = (const float*)d_in[0];
    const float* node_feats = (const float*)d_in[1];
    const float* edge_attrs = (const float*)d_in[2];
    const float* edge_feats = (const float*)d_in[3];
    const int*   edge_index = (const int*)d_in[4];
    const float* W_lin1 = (const float*)d_in[5];
    const float* W_r0 = (const float*)d_in[6];
    const float* W_r1 = (const float*)d_in[7];
    const float* W_r2 = (const float*)d_in[8];
    const float* W_r3 = (const float*)d_in[9];
    const float* W_msg = (const float*)d_in[10];
    const float* W_skip = (const float*)d_in[11];

    float* out = (float*)d_out;                       // N x 576 (msg, transformed in place)
    float* sc  = out + (size_t)N_NODES * MSG_DIM;     // N x 64

    float* wsf = (float*)d_ws;
    float* Wc = wsf;                          // 2048 floats
    float* h  = wsf + 2048;                   // N*64
    int* wsi   = (int*)(wsf + 2048 + (size_t)N_NODES * 64);
    int* counts = wsi;                        // N
    int* start  = wsi + N_NODES;              // N
    int* cursor = wsi + 2 * N_NODES;          // N
    // sorted-record layout (all float4-aligned given 256B-aligned d_ws)
    int*   snd_s = wsi + 3 * N_NODES;                 // E
    float* ef_s  = (float*)(snd_s + N_EDGES);         // E*8
    float* ea_s  = ef_s + (size_t)N_EDGES * 8;        // E*12
    const size_t need_bytes = ((size_t)2048 + (size_t)N_NODES * 64) * 4
                            + (size_t)(3 * N_NODES) * 4
                            + (size_t)N_EDGES * 4
                            + (size_t)N_EDGES * 8 * 4
                            + (size_t)N_EDGES * 12 * 4;
    const bool big_ws = ws_size >= need_bytes;
    int* perm = wsi + 3 * N_NODES;            // E (fallback path only)

    combine_radial<<<1, 256, 0, stream>>>(W_r0, W_r1, W_r2, W_r3, Wc);
    node_linear<<<1250, 256, 0, stream>>>(node_feats, W_lin1, h);

    hipMemsetAsync(counts, 0, N_NODES * sizeof(int), stream);
    hist_kernel<<<(N_EDGES + 255) / 256, 256, 0, stream>>>(edge_index, counts);
    scan_kernel<<<1, 256, 0, stream>>>(counts, start, cursor);

    if (big_ws) {
        scatter_build<<<(N_EDGES + 255) / 256, 256, 0, stream>>>(
            edge_index, edge_feats, edge_attrs, cursor, snd_s, ef_s, ea_s);
        gather_sorted<<<(N_NODES + 3) / 4, 256, 0, stream>>>(
            ef_s, ea_s, snd_s, h, Wc, start, counts, out);
    } else {
        scatter_kernel<<<(N_EDGES + 255) / 256, 256, 0, stream>>>(edge_index, cursor, perm);
        gather_perm<<<(N_NODES + 3) / 4, 256, 0, stream>>>(
            edge_feats, edge_attrs, edge_index, h, Wc, start, counts, perm, out);
    }

    out_transform<<<1250, 256, 0, stream>>>(W_msg, out);
    skip_kernel<<<625, 256, 0, stream>>>(h, node_attrs, W_skip, sc);
}

// Round 6
// 317.821 us; speedup vs baseline: 8.1022x; 1.1434x over previous
//
#include <hip/hip_runtime.h>

#define N_NODES 20000
#define N_EDGES 320000
#define C 64
#define NATTR 10
#define MSG_DIM 576      // C*(1+3+5)
#define WC_COLS 192      // 3*C

// ---------------------------------------------------------------------------
// Kernel 1: collapse the (linear) radial MLP into Wc (8 x 192), one block.
// ---------------------------------------------------------------------------
__global__ void combine_radial(const float* __restrict__ Wr0,
                               const float* __restrict__ Wr1,
                               const float* __restrict__ Wr2,
                               const float* __restrict__ Wr3,
                               float* __restrict__ Wc) {
    __shared__ float T[8 * 64];
    __shared__ float T2[8 * 64];
    const int t = threadIdx.x;  // 256
    const float s0 = 0.35355339059327373f;  // 1/sqrt(8)
    const float s1 = 0.125f;                // 1/8

    for (int i = t; i < 8 * 64; i += 256) {
        int r = i >> 6, c = i & 63;
        float acc = 0.f;
        for (int k = 0; k < 64; ++k) acc += Wr0[r * 64 + k] * Wr1[k * 64 + c];
        T[i] = acc * (s0 * s1);
    }
    __syncthreads();
    for (int i = t; i < 8 * 64; i += 256) {
        int r = i >> 6, c = i & 63;
        float acc = 0.f;
        for (int k = 0; k < 64; ++k) acc += T[r * 64 + k] * Wr2[k * 64 + c];
        T2[i] = acc * s1;
    }
    __syncthreads();
    for (int i = t; i < 8 * WC_COLS; i += 256) {
        int r = i / WC_COLS, c = i % WC_COLS;
        float acc = 0.f;
        for (int k = 0; k < 64; ++k) acc += T2[r * 64 + k] * Wr3[k * WC_COLS + c];
        Wc[i] = acc * s1;
    }
}

// ---------------------------------------------------------------------------
// Kernel 2: h = node_feats @ (W_lin1 / 8).  Also zeroes counts[] (saves a
// separate memset dispatch; hist runs after this in stream order).
// ---------------------------------------------------------------------------
__global__ void node_linear(const float* __restrict__ nf,
                            const float* __restrict__ W,
                            float* __restrict__ h,
                            int* __restrict__ counts) {
    const int t = threadIdx.x;
    if (blockIdx.x < 79) {
        const int i = blockIdx.x * 256 + t;
        if (i < N_NODES) counts[i] = 0;
    }
    __shared__ float Ws[64 * 64];
    __shared__ float row[4][64];
    const int lane = t & 63, wv = t >> 6;
    for (int i = t; i < 4096; i += 256) Ws[i] = W[i] * 0.125f;
    __syncthreads();
    const int base = blockIdx.x * 16;
    for (int it = 0; it < 4; ++it) {
        int n = base + it * 4 + wv;
        if (n >= N_NODES) break;
        row[wv][lane] = nf[(size_t)n * 64 + lane];
        float acc = 0.f;
        #pragma unroll
        for (int k = 0; k < 64; ++k) acc += row[wv][k] * Ws[k * 64 + lane];
        h[(size_t)n * 64 + lane] = acc;
    }
}

// ---------------------------------------------------------------------------
// Sort pipeline: histogram -> scan -> scatter_build (counting sort that
// MATERIALIZES sorted edge records: snd_s, ef_s (8f), ea_s (12f padded)).
// ---------------------------------------------------------------------------
__global__ void hist_kernel(const int* __restrict__ eidx, int* __restrict__ counts) {
    const int e = blockIdx.x * 256 + threadIdx.x;
    if (e < N_EDGES) atomicAdd(&counts[eidx[N_EDGES + e]], 1);
}

#define SCAN_CHUNK 79   // ceil(20000/256) = 79
__global__ void scan_kernel(const int* __restrict__ counts,
                            int* __restrict__ start, int* __restrict__ cursor) {
    __shared__ int tot[256];
    __shared__ int pre[256];
    const int t = threadIdx.x;
    const int base = t * SCAN_CHUNK;
    int s = 0;
    for (int j = 0; j < SCAN_CHUNK; ++j) {
        int idx = base + j;
        if (idx < N_NODES) s += counts[idx];
    }
    tot[t] = s;
    __syncthreads();
    if (t == 0) {
        int a = 0;
        for (int i = 0; i < 256; ++i) { pre[i] = a; a += tot[i]; }
    }
    __syncthreads();
    int a = pre[t];
    for (int j = 0; j < SCAN_CHUNK; ++j) {
        int idx = base + j;
        if (idx < N_NODES) {
            start[idx] = a;
            cursor[idx] = a;
            a += counts[idx];
        }
    }
}

__global__ void scatter_build(const int* __restrict__ eidx,
                              const float* __restrict__ ef,
                              const float* __restrict__ ea,
                              int* __restrict__ cursor,
                              int* __restrict__ snd_s,
                              float* __restrict__ ef_s,
                              float* __restrict__ ea_s) {
    const int e = blockIdx.x * 256 + threadIdx.x;
    if (e >= N_EDGES) return;
    const int r = eidx[N_EDGES + e];
    const int pos = atomicAdd(&cursor[r], 1);
    snd_s[pos] = eidx[e];
    const float4* s4 = reinterpret_cast<const float4*>(ef + (size_t)e * 8);
    float4* d4 = reinterpret_cast<float4*>(ef_s + (size_t)pos * 8);
    d4[0] = s4[0];
    d4[1] = s4[1];
    const float* y = ea + (size_t)e * 9;
    float4* o4 = reinterpret_cast<float4*>(ea_s + (size_t)pos * 12);
    o4[0] = make_float4(y[0], y[1], y[2], y[3]);
    o4[1] = make_float4(y[4], y[5], y[6], y[7]);
    o4[2] = make_float4(y[8], 0.f, 0.f, 0.f);
}

// legacy scatter (fallback when ws too small for records)
__global__ void scatter_kernel(const int* __restrict__ eidx,
                               int* __restrict__ cursor, int* __restrict__ perm) {
    const int e = blockIdx.x * 256 + threadIdx.x;
    if (e < N_EDGES) {
        const int r = eidx[N_EDGES + e];
        const int pos = atomicAdd(&cursor[r], 1);
        perm[pos] = e;
    }
}

// ---------------------------------------------------------------------------
// Kernel 3: gather from SORTED records — one wave per node. All record reads
// are sequential (no indirection); only h[snd] is a (L2-resident) gather.
// ---------------------------------------------------------------------------
__global__ __launch_bounds__(256) void gather_sorted(
                              const float* __restrict__ ef_s,  // E x 8 sorted
                              const float* __restrict__ ea_s,  // E x 12 sorted
                              const int* __restrict__ snd_s,   // E sorted
                              const float* __restrict__ h,     // N x 64
                              const float* __restrict__ Wc,    // 8 x 192
                              const int* __restrict__ start,
                              const int* __restrict__ counts,
                              float* __restrict__ msg) {       // N x 576
    __shared__ float WcL[8 * WC_COLS];
    const int t = threadIdx.x, lane = t & 63, wv = t >> 6;
    for (int i = t; i < 8 * WC_COLS; i += 256) WcL[i] = Wc[i];
    __syncthreads();

    const int n = blockIdx.x * 4 + wv;
    if (n >= N_NODES) return;
    const int s0 = start[n], cnt = counts[n];

    float p0 = 0.f;
    float p1[3] = {0.f, 0.f, 0.f};
    float p2[5] = {0.f, 0.f, 0.f, 0.f, 0.f};

    int j = 0;
    for (; j + 4 <= cnt; j += 4) {
        const size_t r0 = (size_t)(s0 + j);
        int snd[4];
        #pragma unroll
        for (int b = 0; b < 4; ++b) snd[b] = snd_s[r0 + b];
        float xs[4];
        #pragma unroll
        for (int b = 0; b < 4; ++b) xs[b] = h[(size_t)snd[b] * 64 + lane];
        float4 fa[4], fb[4];
        #pragma unroll
        for (int b = 0; b < 4; ++b) {
            const float4* p = reinterpret_cast<const float4*>(ef_s + (r0 + b) * 8);
            fa[b] = p[0];
            fb[b] = p[1];
        }
        float4 ya[4], yb[4], yc[4];
        #pragma unroll
        for (int b = 0; b < 4; ++b) {
            const float4* p = reinterpret_cast<const float4*>(ea_s + (r0 + b) * 12);
            ya[b] = p[0];
            yb[b] = p[1];
            yc[b] = p[2];
        }
        #pragma unroll
        for (int b = 0; b < 4; ++b) {
            const float* fk = reinterpret_cast<const float*>(&fa[b]);
            const float* gk = reinterpret_cast<const float*>(&fb[b]);
            float w0 = fk[0] * WcL[0 * WC_COLS + lane];
            float w1 = fk[0] * WcL[0 * WC_COLS + 64 + lane];
            float w2 = fk[0] * WcL[0 * WC_COLS + 128 + lane];
            #pragma unroll
            for (int k = 1; k < 4; ++k) {
                w0 += fk[k] * WcL[k * WC_COLS + lane];
                w1 += fk[k] * WcL[k * WC_COLS + 64 + lane];
                w2 += fk[k] * WcL[k * WC_COLS + 128 + lane];
            }
            #pragma unroll
            for (int k = 0; k < 4; ++k) {
                w0 += gk[k] * WcL[(k + 4) * WC_COLS + lane];
                w1 += gk[k] * WcL[(k + 4) * WC_COLS + 64 + lane];
                w2 += gk[k] * WcL[(k + 4) * WC_COLS + 128 + lane];
            }
            const float a0 = xs[b] * w0, a1 = xs[b] * w1, a2 = xs[b] * w2;
            p0    += a0 * ya[b].x;
            p1[0] += a1 * ya[b].y;
            p1[1] += a1 * ya[b].z;
            p1[2] += a1 * ya[b].w;
            p2[0] += a2 * yb[b].x;
            p2[1] += a2 * yb[b].y;
            p2[2] += a2 * yb[b].z;
            p2[3] += a2 * yb[b].w;
            p2[4] += a2 * yc[b].x;
        }
    }
    for (; j < cnt; ++j) {
        const size_t r0 = (size_t)(s0 + j);
        const int snd = snd_s[r0];
        const float xs = h[(size_t)snd * 64 + lane];
        const float4* pf = reinterpret_cast<const float4*>(ef_s + r0 * 8);
        const float4 fa = pf[0], fb = pf[1];
        const float4* py = reinterpret_cast<const float4*>(ea_s + r0 * 12);
        const float4 ya = py[0], yb = py[1], yc = py[2];
        const float* fk = reinterpret_cast<const float*>(&fa);
        const float* gk = reinterpret_cast<const float*>(&fb);
        float w0 = fk[0] * WcL[0 * WC_COLS + lane];
        float w1 = fk[0] * WcL[0 * WC_COLS + 64 + lane];
        float w2 = fk[0] * WcL[0 * WC_COLS + 128 + lane];
        #pragma unroll
        for (int k = 1; k < 4; ++k) {
            w0 += fk[k] * WcL[k * WC_COLS + lane];
            w1 += fk[k] * WcL[k * WC_COLS + 64 + lane];
            w2 += fk[k] * WcL[k * WC_COLS + 128 + lane];
        }
        #pragma unroll
        for (int k = 0; k < 4; ++k) {
            w0 += gk[k] * WcL[(k + 4) * WC_COLS + lane];
            w1 += gk[k] * WcL[(k + 4) * WC_COLS + 64 + lane];
            w2 += gk[k] * WcL[(k + 4) * WC_COLS + 128 + lane];
        }
        const float a0 = xs * w0, a1 = xs * w1, a2 = xs * w2;
        p0    += a0 * ya.x;
        p1[0] += a1 * ya.y;
        p1[1] += a1 * ya.z;
        p1[2] += a1 * ya.w;
        p2[0] += a2 * yb.x;
        p2[1] += a2 * yb.y;
        p2[2] += a2 * yb.z;
        p2[3] += a2 * yb.w;
        p2[4] += a2 * yc.x;
    }

    float* mrow = msg + (size_t)n * MSG_DIM;
    mrow[lane] = p0;
    #pragma unroll
    for (int m = 0; m < 3; ++m) mrow[64 + lane * 3 + m] = p1[m];
    #pragma unroll
    for (int m = 0; m < 5; ++m) mrow[256 + lane * 5 + m] = p2[m];
}

// legacy perm-based gather (fallback)
__global__ __launch_bounds__(256) void gather_perm(
                              const float* __restrict__ ef,
                              const float* __restrict__ ea,
                              const int* __restrict__ eidx,
                              const float* __restrict__ h,
                              const float* __restrict__ Wc,
                              const int* __restrict__ start,
                              const int* __restrict__ counts,
                              const int* __restrict__ perm,
                              float* __restrict__ msg) {
    __shared__ float WcL[8 * WC_COLS];
    const int t = threadIdx.x, lane = t & 63, wv = t >> 6;
    for (int i = t; i < 8 * WC_COLS; i += 256) WcL[i] = Wc[i];
    __syncthreads();
    const int n = blockIdx.x * 4 + wv;
    if (n >= N_NODES) return;
    const int s0 = start[n], cnt = counts[n];
    float p0 = 0.f;
    float p1[3] = {0.f, 0.f, 0.f};
    float p2[5] = {0.f, 0.f, 0.f, 0.f, 0.f};
    for (int j = 0; j < cnt; ++j) {
        const int e = perm[s0 + j];
        const int snd = eidx[e];
        const float xs = h[(size_t)snd * 64 + lane];
        const float4* ef4 = reinterpret_cast<const float4*>(ef + (size_t)e * 8);
        const float4 fa = ef4[0], fb = ef4[1];
        const float* fk = reinterpret_cast<const float*>(&fa);
        const float* gk = reinterpret_cast<const float*>(&fb);
        float w0 = fk[0] * WcL[0 * WC_COLS + lane];
        float w1 = fk[0] * WcL[0 * WC_COLS + 64 + lane];
        float w2 = fk[0] * WcL[0 * WC_COLS + 128 + lane];
        #pragma unroll
        for (int k = 1; k < 4; ++k) {
            w0 += fk[k] * WcL[k * WC_COLS + lane];
            w1 += fk[k] * WcL[k * WC_COLS + 64 + lane];
            w2 += fk[k] * WcL[k * WC_COLS + 128 + lane];
        }
        #pragma unroll
        for (int k = 0; k < 4; ++k) {
            w0 += gk[k] * WcL[(k + 4) * WC_COLS + lane];
            w1 += gk[k] * WcL[(k + 4) * WC_COLS + 64 + lane];
            w2 += gk[k] * WcL[(k + 4) * WC_COLS + 128 + lane];
        }
        const float* y = ea + (size_t)e * 9;
        const float a0 = xs * w0, a1 = xs * w1, a2 = xs * w2;
        p0    += a0 * y[0];
        p1[0] += a1 * y[1];
        p1[1] += a1 * y[2];
        p1[2] += a1 * y[3];
        p2[0] += a2 * y[4];
        p2[1] += a2 * y[5];
        p2[2] += a2 * y[6];
        p2[3] += a2 * y[7];
        p2[4] += a2 * y[8];
    }
    float* mrow = msg + (size_t)n * MSG_DIM;
    mrow[lane] = p0;
    #pragma unroll
    for (int m = 0; m < 3; ++m) mrow[64 + lane * 3 + m] = p1[m];
    #pragma unroll
    for (int m = 0; m < 5; ++m) mrow[256 + lane * 5 + m] = p2[m];
}

// ---------------------------------------------------------------------------
// Kernel 4: per-node W_msg transform. 8 consecutive nodes / block (their msg
// rows are one contiguous 18 KB span) staged into LDS with coalesced float4
// copies; compute reads c as LDS float4 broadcasts and W as conflict-free
// stride-1 b32 reads (amortized over the wave's 2 nodes). Grid 2500.
// ---------------------------------------------------------------------------
__global__ __launch_bounds__(256) void out_transform(
        const float* __restrict__ Wmsg,  // 3*64*64
        float* __restrict__ out) {       // N x 576 (in = msg, out in place)
    __shared__ float WL[3 * 64 * 64];               // 48 KB
    __shared__ __align__(16) float stage[8 * MSG_DIM];  // 18 KB
    const int t = threadIdx.x, lane = t & 63, wv = t >> 6;
    for (int i = t; i < 3 * 64 * 64; i += 256) WL[i] = Wmsg[i];

    // stage the block's 8 consecutive msg rows (one contiguous span)
    {
        const float4* src = reinterpret_cast<const float4*>(
            out + (size_t)blockIdx.x * 8 * MSG_DIM);
        float4* dst = reinterpret_cast<float4*>(stage);
        #pragma unroll
        for (int i = 0; i < 4; ++i) dst[t + 256 * i] = src[t + 256 * i];
        if (t < 128) dst[t + 1024] = src[t + 1024];
    }
    __syncthreads();
    const float scale = 1.f / 128.f;  // 1/(sqrt(64)*16)

    // wave wv owns rows 2*wv and 2*wv+1
    const int r0 = wv * 2;
    const float* rowA = stage + (size_t)r0 * MSG_DIM;
    const float* rowB = rowA + MSG_DIM;
    float oA[9] = {0.f, 0.f, 0.f, 0.f, 0.f, 0.f, 0.f, 0.f, 0.f};
    float oB[9] = {0.f, 0.f, 0.f, 0.f, 0.f, 0.f, 0.f, 0.f, 0.f};

    #pragma unroll 1
    for (int u8 = 0; u8 < 8; ++u8) {
        const int u0 = u8 * 8;
        float w0[8], w1[8], w2[8];
        #pragma unroll
        for (int j = 0; j < 8; ++j) {
            w0[j] = WL[(u0 + j) * 64 + lane];
            w1[j] = WL[4096 + (u0 + j) * 64 + lane];
            w2[j] = WL[8192 + (u0 + j) * 64 + lane];
        }
        #pragma unroll
        for (int rr = 0; rr < 2; ++rr) {
            const float* row = rr ? rowB : rowA;
            float* o = rr ? oB : oA;
            float c0[8], c1[24], c2[40];
            {
                const float4* p = reinterpret_cast<const float4*>(row + u0);
                #pragma unroll
                for (int q = 0; q < 2; ++q) {
                    float4 v = p[q];
                    c0[q * 4 + 0] = v.x; c0[q * 4 + 1] = v.y;
                    c0[q * 4 + 2] = v.z; c0[q * 4 + 3] = v.w;
                }
            }
            {
                const float4* p = reinterpret_cast<const float4*>(row + 64 + u0 * 3);
                #pragma unroll
                for (int q = 0; q < 6; ++q) {
                    float4 v = p[q];
                    c1[q * 4 + 0] = v.x; c1[q * 4 + 1] = v.y;
                    c1[q * 4 + 2] = v.z; c1[q * 4 + 3] = v.w;
                }
            }
            {
                const float4* p = reinterpret_cast<const float4*>(row + 256 + u0 * 5);
                #pragma unroll
                for (int q = 0; q < 10; ++q) {
                    float4 v = p[q];
                    c2[q * 4 + 0] = v.x; c2[q * 4 + 1] = v.y;
                    c2[q * 4 + 2] = v.z; c2[q * 4 + 3] = v.w;
                }
            }
            #pragma unroll
            for (int j = 0; j < 8; ++j) {
                o[0] += c0[j] * w0[j];
                #pragma unroll
                for (int m = 0; m < 3; ++m) o[1 + m] += c1[j * 3 + m] * w1[j];
                #pragma unroll
                for (int m = 0; m < 5; ++m) o[4 + m] += c2[j * 5 + m] * w2[j];
            }
        }
    }
    float* opA = out + ((size_t)blockIdx.x * 8 + r0) * MSG_DIM + lane * 9;
    float* opB = opA + MSG_DIM;
    #pragma unroll
    for (int m = 0; m < 9; ++m) opA[m] = oA[m] * scale;
    #pragma unroll
    for (int m = 0; m < 9; ++m) opB[m] = oB[m] * scale;
}

// ---------------------------------------------------------------------------
// Kernel 5: sc[n,w] = sum_{u,v} h[n,u]*attrs[n,v]*W_skip[u,v,w] / sqrt(640)
// ---------------------------------------------------------------------------
__global__ __launch_bounds__(256) void skip_kernel(
                            const float* __restrict__ h,
                            const float* __restrict__ attrs,
                            const float* __restrict__ Wskip,  // 64*10*64
                            float* __restrict__ sc) {
    __shared__ float hl[32 * 64];
    const int t = threadIdx.x, lane = t & 63, wv = t >> 6;
    const int nb = blockIdx.x * 32;
    for (int i = t; i < 32 * 64; i += 256) hl[i] = h[(size_t)(nb + (i >> 6)) * 64 + (i & 63)];
    __syncthreads();

    float alr[8][NATTR];
    #pragma unroll
    for (int i = 0; i < 8; ++i) {
        const float* ap = attrs + (size_t)(nb + wv + 4 * i) * NATTR;
        #pragma unroll
        for (int v = 0; v < NATTR; ++v) alr[i][v] = ap[v];
    }

    float acc[8] = {0.f, 0.f, 0.f, 0.f, 0.f, 0.f, 0.f, 0.f};
    #pragma unroll 1
    for (int u4 = 0; u4 < 16; ++u4) {
        const int u0 = u4 * 4;
        float4 hu[8];
        #pragma unroll
        for (int i = 0; i < 8; ++i)
            hu[i] = *reinterpret_cast<const float4*>(&hl[(wv + 4 * i) * 64 + u0]);
        #pragma unroll
        for (int uu = 0; uu < 4; ++uu) {
            float tmp[8] = {0.f, 0.f, 0.f, 0.f, 0.f, 0.f, 0.f, 0.f};
            #pragma unroll
            for (int v = 0; v < NATTR; ++v) {
                const float wk = Wskip[((u0 + uu) * NATTR + v) * 64 + lane];
                #pragma unroll
                for (int i = 0; i < 8; ++i) tmp[i] += alr[i][v] * wk;
            }
            #pragma unroll
            for (int i = 0; i < 8; ++i) {
                const float huv = (uu == 0) ? hu[i].x : (uu == 1) ? hu[i].y
                                 : (uu == 2) ? hu[i].z : hu[i].w;
                acc[i] += huv * tmp[i];
            }
        }
    }
    const float scale = 0.03952847075210474f;  // 1/sqrt(640)
    #pragma unroll
    for (int i = 0; i < 8; ++i)
        sc[(size_t)(nb + wv + 4 * i) * 64 + lane] = acc[i] * scale;
}

// ---------------------------------------------------------------------------
extern "C" void kernel_launch(void* const* d_in, const int* in_sizes, int n_in,
                              void* d_out, int out_size, void* d_ws, size_t ws_size,
                              hipStream_t stream) {
    const float* node_attrs = (const float*)d_in[0];
    const float* node_feats = (const float*)d_in[1];
    const float* edge_attrs = (const float*)d_in[2];
    const float* edge_feats = (const float*)d_in[3];
    const int*   edge_index = (const int*)d_in[4];
    const float* W_lin1 = (const float*)d_in[5];
    const float* W_r0 = (const float*)d_in[6];
    const float* W_r1 = (const float*)d_in[7];
    const float* W_r2 = (const float*)d_in[8];
    const float* W_r3 = (const float*)d_in[9];
    const float* W_msg = (const float*)d_in[10];
    const float* W_skip = (const float*)d_in[11];

    float* out = (float*)d_out;                       // N x 576 (msg, transformed in place)
    float* sc  = out + (size_t)N_NODES * MSG_DIM;     // N x 64

    float* wsf = (float*)d_ws;
    float* Wc = wsf;                          // 2048 floats
    float* h  = wsf + 2048;                   // N*64
    int* wsi   = (int*)(wsf + 2048 + (size_t)N_NODES * 64);
    int* counts = wsi;                        // N
    int* start  = wsi + N_NODES;              // N
    int* cursor = wsi + 2 * N_NODES;          // N
    int*   snd_s = wsi + 3 * N_NODES;                 // E
    float* ef_s  = (float*)(snd_s + N_EDGES);         // E*8
    float* ea_s  = ef_s + (size_t)N_EDGES * 8;        // E*12
    const size_t need_bytes = ((size_t)2048 + (size_t)N_NODES * 64) * 4
                            + (size_t)(3 * N_NODES) * 4
                            + (size_t)N_EDGES * 4
                            + (size_t)N_EDGES * 8 * 4
                            + (size_t)N_EDGES * 12 * 4;
    const bool big_ws = ws_size >= need_bytes;
    int* perm = wsi + 3 * N_NODES;            // E (fallback path only)

    combine_radial<<<1, 256, 0, stream>>>(W_r0, W_r1, W_r2, W_r3, Wc);
    node_linear<<<1250, 256, 0, stream>>>(node_feats, W_lin1, h, counts);

    hist_kernel<<<(N_EDGES + 255) / 256, 256, 0, stream>>>(edge_index, counts);
    scan_kernel<<<1, 256, 0, stream>>>(counts, start, cursor);

    if (big_ws) {
        scatter_build<<<(N_EDGES + 255) / 256, 256, 0, stream>>>(
            edge_index, edge_feats, edge_attrs, cursor, snd_s, ef_s, ea_s);
        gather_sorted<<<(N_NODES + 3) / 4, 256, 0, stream>>>(
            ef_s, ea_s, snd_s, h, Wc, start, counts, out);
    } else {
        scatter_kernel<<<(N_EDGES + 255) / 256, 256, 0, stream>>>(edge_index, cursor, perm);
        gather_perm<<<(N_NODES + 3) / 4, 256, 0, stream>>>(
            edge_feats, edge_attrs, edge_index, h, Wc, start, counts, perm, out);
    }

    out_transform<<<2500, 256, 0, stream>>>(W_msg, out);
    skip_kernel<<<625, 256, 0, stream>>>(h, node_attrs, W_skip, sc);
}

// Round 7
// 310.967 us; speedup vs baseline: 8.2808x; 1.0220x over previous
//
#include <hip/hip_runtime.h>

#define N_NODES 20000
#define N_EDGES 320000
#define C 64
#define NATTR 10
#define MSG_DIM 576      // C*(1+3+5)
#define WC_COLS 192      // 3*C

// ---------------------------------------------------------------------------
// Kernel 1: collapse the (linear) radial MLP into Wc (8 x 192), one block.
// ---------------------------------------------------------------------------
__global__ void combine_radial(const float* __restrict__ Wr0,
                               const float* __restrict__ Wr1,
                               const float* __restrict__ Wr2,
                               const float* __restrict__ Wr3,
                               float* __restrict__ Wc) {
    __shared__ float T[8 * 64];
    __shared__ float T2[8 * 64];
    const int t = threadIdx.x;  // 256
    const float s0 = 0.35355339059327373f;  // 1/sqrt(8)
    const float s1 = 0.125f;                // 1/8

    for (int i = t; i < 8 * 64; i += 256) {
        int r = i >> 6, c = i & 63;
        float acc = 0.f;
        for (int k = 0; k < 64; ++k) acc += Wr0[r * 64 + k] * Wr1[k * 64 + c];
        T[i] = acc * (s0 * s1);
    }
    __syncthreads();
    for (int i = t; i < 8 * 64; i += 256) {
        int r = i >> 6, c = i & 63;
        float acc = 0.f;
        for (int k = 0; k < 64; ++k) acc += T[r * 64 + k] * Wr2[k * 64 + c];
        T2[i] = acc * s1;
    }
    __syncthreads();
    for (int i = t; i < 8 * WC_COLS; i += 256) {
        int r = i / WC_COLS, c = i % WC_COLS;
        float acc = 0.f;
        for (int k = 0; k < 64; ++k) acc += T2[r * 64 + k] * Wr3[k * WC_COLS + c];
        Wc[i] = acc * s1;
    }
}

// ---------------------------------------------------------------------------
// Kernel 2: h = node_feats @ (W_lin1 / 8).  Also zeroes counts[].
// ---------------------------------------------------------------------------
__global__ void node_linear(const float* __restrict__ nf,
                            const float* __restrict__ W,
                            float* __restrict__ h,
                            int* __restrict__ counts) {
    const int t = threadIdx.x;
    if (blockIdx.x < 79) {
        const int i = blockIdx.x * 256 + t;
        if (i < N_NODES) counts[i] = 0;
    }
    __shared__ float Ws[64 * 64];
    __shared__ float row[4][64];
    const int lane = t & 63, wv = t >> 6;
    for (int i = t; i < 4096; i += 256) Ws[i] = W[i] * 0.125f;
    __syncthreads();
    const int base = blockIdx.x * 16;
    for (int it = 0; it < 4; ++it) {
        int n = base + it * 4 + wv;
        if (n >= N_NODES) break;
        row[wv][lane] = nf[(size_t)n * 64 + lane];
        float acc = 0.f;
        #pragma unroll
        for (int k = 0; k < 64; ++k) acc += row[wv][k] * Ws[k * 64 + lane];
        h[(size_t)n * 64 + lane] = acc;
    }
}

// ---------------------------------------------------------------------------
// Sort pipeline: histogram -> scan -> scatter_build.
// ---------------------------------------------------------------------------
__global__ void hist_kernel(const int* __restrict__ eidx, int* __restrict__ counts) {
    const int e = blockIdx.x * 256 + threadIdx.x;
    if (e < N_EDGES) atomicAdd(&counts[eidx[N_EDGES + e]], 1);
}

#define SCAN_CHUNK 79   // ceil(20000/256) = 79
__global__ void scan_kernel(const int* __restrict__ counts,
                            int* __restrict__ start, int* __restrict__ cursor) {
    __shared__ int tot[256];
    __shared__ int pre[256];
    const int t = threadIdx.x;
    const int base = t * SCAN_CHUNK;
    int s = 0;
    for (int j = 0; j < SCAN_CHUNK; ++j) {
        int idx = base + j;
        if (idx < N_NODES) s += counts[idx];
    }
    tot[t] = s;
    __syncthreads();
    if (t == 0) {
        int a = 0;
        for (int i = 0; i < 256; ++i) { pre[i] = a; a += tot[i]; }
    }
    __syncthreads();
    int a = pre[t];
    for (int j = 0; j < SCAN_CHUNK; ++j) {
        int idx = base + j;
        if (idx < N_NODES) {
            start[idx] = a;
            cursor[idx] = a;
            a += counts[idx];
        }
    }
}

__global__ void scatter_build(const int* __restrict__ eidx,
                              const float* __restrict__ ef,
                              const float* __restrict__ ea,
                              int* __restrict__ cursor,
                              int* __restrict__ snd_s,
                              float* __restrict__ ef_s,
                              float* __restrict__ ea_s) {
    const int e = blockIdx.x * 256 + threadIdx.x;
    if (e >= N_EDGES) return;
    const int r = eidx[N_EDGES + e];
    const int pos = atomicAdd(&cursor[r], 1);
    snd_s[pos] = eidx[e];
    const float4* s4 = reinterpret_cast<const float4*>(ef + (size_t)e * 8);
    float4* d4 = reinterpret_cast<float4*>(ef_s + (size_t)pos * 8);
    d4[0] = s4[0];
    d4[1] = s4[1];
    const float* y = ea + (size_t)e * 9;
    float4* o4 = reinterpret_cast<float4*>(ea_s + (size_t)pos * 12);
    o4[0] = make_float4(y[0], y[1], y[2], y[3]);
    o4[1] = make_float4(y[4], y[5], y[6], y[7]);
    o4[2] = make_float4(y[8], 0.f, 0.f, 0.f);
}

// legacy scatter (fallback when ws too small for records)
__global__ void scatter_kernel(const int* __restrict__ eidx,
                               int* __restrict__ cursor, int* __restrict__ perm) {
    const int e = blockIdx.x * 256 + threadIdx.x;
    if (e < N_EDGES) {
        const int r = eidx[N_EDGES + e];
        const int pos = atomicAdd(&cursor[r], 1);
        perm[pos] = e;
    }
}

// ---------------------------------------------------------------------------
// Kernel 3: gather from SORTED records — TWO waves per node (each half the
// edges), Wc hoisted to registers (no LDS in hot loop), partials combined
// via LDS. Block = 4 waves = 2 nodes; grid = N/2.
// ---------------------------------------------------------------------------
__global__ __launch_bounds__(256, 4) void gather_sorted(
                              const float* __restrict__ ef_s,  // E x 8 sorted
                              const float* __restrict__ ea_s,  // E x 12 sorted
                              const int* __restrict__ snd_s,   // E sorted
                              const float* __restrict__ h,     // N x 64
                              const float* __restrict__ Wc,    // 8 x 192
                              const int* __restrict__ start,
                              const int* __restrict__ counts,
                              float* __restrict__ msg) {       // N x 576
    __shared__ float part[2][9][64];
    const int t = threadIdx.x, lane = t & 63, wv = t >> 6;
    const int g = wv >> 1;               // node slot within block (0,1)
    const int half = wv & 1;             // which half of the edge list
    const int n = blockIdx.x * 2 + g;

    // hoist Wc into registers: invariant over edges (depends on lane only)
    float wc0[8], wc1[8], wc2[8];
    #pragma unroll
    for (int k = 0; k < 8; ++k) {
        wc0[k] = Wc[k * WC_COLS + lane];
        wc1[k] = Wc[k * WC_COLS + 64 + lane];
        wc2[k] = Wc[k * WC_COLS + 128 + lane];
    }

    float p0 = 0.f;
    float p1[3] = {0.f, 0.f, 0.f};
    float p2[5] = {0.f, 0.f, 0.f, 0.f, 0.f};

    if (n < N_NODES) {
        const int s0 = start[n], cnt = counts[n];
        const int jbeg = half ? (cnt >> 1) : 0;
        const int jend = half ? cnt : (cnt >> 1);

        int j = jbeg;
        for (; j + 4 <= jend; j += 4) {
            const size_t r0 = (size_t)(s0 + j);
            // independent loads first: senders + records
            int snd[4];
            #pragma unroll
            for (int b = 0; b < 4; ++b) snd[b] = snd_s[r0 + b];
            float4 fa[4], fb[4];
            #pragma unroll
            for (int b = 0; b < 4; ++b) {
                const float4* p = reinterpret_cast<const float4*>(ef_s + (r0 + b) * 8);
                fa[b] = p[0];
                fb[b] = p[1];
            }
            float4 ya[4], yb[4], yc[4];
            #pragma unroll
            for (int b = 0; b < 4; ++b) {
                const float4* p = reinterpret_cast<const float4*>(ea_s + (r0 + b) * 12);
                ya[b] = p[0];
                yb[b] = p[1];
                yc[b] = p[2];
            }
            // dependent gather last (snd wait happens with records in flight)
            float xs[4];
            #pragma unroll
            for (int b = 0; b < 4; ++b) xs[b] = h[(size_t)snd[b] * 64 + lane];

            #pragma unroll
            for (int b = 0; b < 4; ++b) {
                const float* fk = reinterpret_cast<const float*>(&fa[b]);
                const float* gk = reinterpret_cast<const float*>(&fb[b]);
                float w0 = fk[0] * wc0[0], w1 = fk[0] * wc1[0], w2 = fk[0] * wc2[0];
                #pragma unroll
                for (int k = 1; k < 4; ++k) {
                    w0 += fk[k] * wc0[k];
                    w1 += fk[k] * wc1[k];
                    w2 += fk[k] * wc2[k];
                }
                #pragma unroll
                for (int k = 0; k < 4; ++k) {
                    w0 += gk[k] * wc0[k + 4];
                    w1 += gk[k] * wc1[k + 4];
                    w2 += gk[k] * wc2[k + 4];
                }
                const float a0 = xs[b] * w0, a1 = xs[b] * w1, a2 = xs[b] * w2;
                p0    += a0 * ya[b].x;
                p1[0] += a1 * ya[b].y;
                p1[1] += a1 * ya[b].z;
                p1[2] += a1 * ya[b].w;
                p2[0] += a2 * yb[b].x;
                p2[1] += a2 * yb[b].y;
                p2[2] += a2 * yb[b].z;
                p2[3] += a2 * yb[b].w;
                p2[4] += a2 * yc[b].x;
            }
        }
        for (; j < jend; ++j) {
            const size_t r0 = (size_t)(s0 + j);
            const int snd = snd_s[r0];
            const float4* pf = reinterpret_cast<const float4*>(ef_s + r0 * 8);
            const float4 fa = pf[0], fb = pf[1];
            const float4* py = reinterpret_cast<const float4*>(ea_s + r0 * 12);
            const float4 ya = py[0], yb = py[1], yc = py[2];
            const float xs = h[(size_t)snd * 64 + lane];
            const float* fk = reinterpret_cast<const float*>(&fa);
            const float* gk = reinterpret_cast<const float*>(&fb);
            float w0 = fk[0] * wc0[0], w1 = fk[0] * wc1[0], w2 = fk[0] * wc2[0];
            #pragma unroll
            for (int k = 1; k < 4; ++k) {
                w0 += fk[k] * wc0[k];
                w1 += fk[k] * wc1[k];
                w2 += fk[k] * wc2[k];
            }
            #pragma unroll
            for (int k = 0; k < 4; ++k) {
                w0 += gk[k] * wc0[k + 4];
                w1 += gk[k] * wc1[k + 4];
                w2 += gk[k] * wc2[k + 4];
            }
            const float a0 = xs * w0, a1 = xs * w1, a2 = xs * w2;
            p0    += a0 * ya.x;
            p1[0] += a1 * ya.y;
            p1[1] += a1 * ya.z;
            p1[2] += a1 * ya.w;
            p2[0] += a2 * yb.x;
            p2[1] += a2 * yb.y;
            p2[2] += a2 * yb.z;
            p2[3] += a2 * yb.w;
            p2[4] += a2 * yc.x;
        }
    }

    // combine: half 1 publishes, half 0 adds + writes
    if (half) {
        part[g][0][lane] = p0;
        #pragma unroll
        for (int m = 0; m < 3; ++m) part[g][1 + m][lane] = p1[m];
        #pragma unroll
        for (int m = 0; m < 5; ++m) part[g][4 + m][lane] = p2[m];
    }
    __syncthreads();
    if (!half && n < N_NODES) {
        float* mrow = msg + (size_t)n * MSG_DIM;
        mrow[lane] = p0 + part[g][0][lane];
        #pragma unroll
        for (int m = 0; m < 3; ++m)
            mrow[64 + lane * 3 + m] = p1[m] + part[g][1 + m][lane];
        #pragma unroll
        for (int m = 0; m < 5; ++m)
            mrow[256 + lane * 5 + m] = p2[m] + part[g][4 + m][lane];
    }
}

// legacy perm-based gather (fallback)
__global__ __launch_bounds__(256) void gather_perm(
                              const float* __restrict__ ef,
                              const float* __restrict__ ea,
                              const int* __restrict__ eidx,
                              const float* __restrict__ h,
                              const float* __restrict__ Wc,
                              const int* __restrict__ start,
                              const int* __restrict__ counts,
                              const int* __restrict__ perm,
                              float* __restrict__ msg) {
    __shared__ float WcL[8 * WC_COLS];
    const int t = threadIdx.x, lane = t & 63, wv = t >> 6;
    for (int i = t; i < 8 * WC_COLS; i += 256) WcL[i] = Wc[i];
    __syncthreads();
    const int n = blockIdx.x * 4 + wv;
    if (n >= N_NODES) return;
    const int s0 = start[n], cnt = counts[n];
    float p0 = 0.f;
    float p1[3] = {0.f, 0.f, 0.f};
    float p2[5] = {0.f, 0.f, 0.f, 0.f, 0.f};
    for (int j = 0; j < cnt; ++j) {
        const int e = perm[s0 + j];
        const int snd = eidx[e];
        const float xs = h[(size_t)snd * 64 + lane];
        const float4* ef4 = reinterpret_cast<const float4*>(ef + (size_t)e * 8);
        const float4 fa = ef4[0], fb = ef4[1];
        const float* fk = reinterpret_cast<const float*>(&fa);
        const float* gk = reinterpret_cast<const float*>(&fb);
        float w0 = fk[0] * WcL[0 * WC_COLS + lane];
        float w1 = fk[0] * WcL[0 * WC_COLS + 64 + lane];
        float w2 = fk[0] * WcL[0 * WC_COLS + 128 + lane];
        #pragma unroll
        for (int k = 1; k < 4; ++k) {
            w0 += fk[k] * WcL[k * WC_COLS + lane];
            w1 += fk[k] * WcL[k * WC_COLS + 64 + lane];
            w2 += fk[k] * WcL[k * WC_COLS + 128 + lane];
        }
        #pragma unroll
        for (int k = 0; k < 4; ++k) {
            w0 += gk[k] * WcL[(k + 4) * WC_COLS + lane];
            w1 += gk[k] * WcL[(k + 4) * WC_COLS + 64 + lane];
            w2 += gk[k] * WcL[(k + 4) * WC_COLS + 128 + lane];
        }
        const float* y = ea + (size_t)e * 9;
        const float a0 = xs * w0, a1 = xs * w1, a2 = xs * w2;
        p0    += a0 * y[0];
        p1[0] += a1 * y[1];
        p1[1] += a1 * y[2];
        p1[2] += a1 * y[3];
        p2[0] += a2 * y[4];
        p2[1] += a2 * y[5];
        p2[2] += a2 * y[6];
        p2[3] += a2 * y[7];
        p2[4] += a2 * y[8];
    }
    float* mrow = msg + (size_t)n * MSG_DIM;
    mrow[lane] = p0;
    #pragma unroll
    for (int m = 0; m < 3; ++m) mrow[64 + lane * 3 + m] = p1[m];
    #pragma unroll
    for (int m = 0; m < 5; ++m) mrow[256 + lane * 5 + m] = p2[m];
}

// ---------------------------------------------------------------------------
// Kernel 4: per-node W_msg transform. 8 consecutive nodes / block staged
// into LDS with coalesced float4 copies; W in LDS; grid 2500.
// ---------------------------------------------------------------------------
__global__ __launch_bounds__(256) void out_transform(
        const float* __restrict__ Wmsg,  // 3*64*64
        float* __restrict__ out) {       // N x 576 (in = msg, out in place)
    __shared__ float WL[3 * 64 * 64];               // 48 KB
    __shared__ __align__(16) float stage[8 * MSG_DIM];  // 18 KB
    const int t = threadIdx.x, lane = t & 63, wv = t >> 6;
    for (int i = t; i < 3 * 64 * 64; i += 256) WL[i] = Wmsg[i];

    {
        const float4* src = reinterpret_cast<const float4*>(
            out + (size_t)blockIdx.x * 8 * MSG_DIM);
        float4* dst = reinterpret_cast<float4*>(stage);
        #pragma unroll
        for (int i = 0; i < 4; ++i) dst[t + 256 * i] = src[t + 256 * i];
        if (t < 128) dst[t + 1024] = src[t + 1024];
    }
    __syncthreads();
    const float scale = 1.f / 128.f;  // 1/(sqrt(64)*16)

    const int r0 = wv * 2;
    const float* rowA = stage + (size_t)r0 * MSG_DIM;
    const float* rowB = rowA + MSG_DIM;
    float oA[9] = {0.f, 0.f, 0.f, 0.f, 0.f, 0.f, 0.f, 0.f, 0.f};
    float oB[9] = {0.f, 0.f, 0.f, 0.f, 0.f, 0.f, 0.f, 0.f, 0.f};

    #pragma unroll 1
    for (int u8 = 0; u8 < 8; ++u8) {
        const int u0 = u8 * 8;
        float w0[8], w1[8], w2[8];
        #pragma unroll
        for (int j = 0; j < 8; ++j) {
            w0[j] = WL[(u0 + j) * 64 + lane];
            w1[j] = WL[4096 + (u0 + j) * 64 + lane];
            w2[j] = WL[8192 + (u0 + j) * 64 + lane];
        }
        #pragma unroll
        for (int rr = 0; rr < 2; ++rr) {
            const float* row = rr ? rowB : rowA;
            float* o = rr ? oB : oA;
            float c0[8], c1[24], c2[40];
            {
                const float4* p = reinterpret_cast<const float4*>(row + u0);
                #pragma unroll
                for (int q = 0; q < 2; ++q) {
                    float4 v = p[q];
                    c0[q * 4 + 0] = v.x; c0[q * 4 + 1] = v.y;
                    c0[q * 4 + 2] = v.z; c0[q * 4 + 3] = v.w;
                }
            }
            {
                const float4* p = reinterpret_cast<const float4*>(row + 64 + u0 * 3);
                #pragma unroll
                for (int q = 0; q < 6; ++q) {
                    float4 v = p[q];
                    c1[q * 4 + 0] = v.x; c1[q * 4 + 1] = v.y;
                    c1[q * 4 + 2] = v.z; c1[q * 4 + 3] = v.w;
                }
            }
            {
                const float4* p = reinterpret_cast<const float4*>(row + 256 + u0 * 5);
                #pragma unroll
                for (int q = 0; q < 10; ++q) {
                    float4 v = p[q];
                    c2[q * 4 + 0] = v.x; c2[q * 4 + 1] = v.y;
                    c2[q * 4 + 2] = v.z; c2[q * 4 + 3] = v.w;
                }
            }
            #pragma unroll
            for (int j = 0; j < 8; ++j) {
                o[0] += c0[j] * w0[j];
                #pragma unroll
                for (int m = 0; m < 3; ++m) o[1 + m] += c1[j * 3 + m] * w1[j];
                #pragma unroll
                for (int m = 0; m < 5; ++m) o[4 + m] += c2[j * 5 + m] * w2[j];
            }
        }
    }
    float* opA = out + ((size_t)blockIdx.x * 8 + r0) * MSG_DIM + lane * 9;
    float* opB = opA + MSG_DIM;
    #pragma unroll
    for (int m = 0; m < 9; ++m) opA[m] = oA[m] * scale;
    #pragma unroll
    for (int m = 0; m < 9; ++m) opB[m] = oB[m] * scale;
}

// ---------------------------------------------------------------------------
// Kernel 5: sc[n,w] = sum_{u,v} h[n,u]*attrs[n,v]*W_skip[u,v,w] / sqrt(640)
// ---------------------------------------------------------------------------
__global__ __launch_bounds__(256) void skip_kernel(
                            const float* __restrict__ h,
                            const float* __restrict__ attrs,
                            const float* __restrict__ Wskip,  // 64*10*64
                            float* __restrict__ sc) {
    __shared__ float hl[32 * 64];
    const int t = threadIdx.x, lane = t & 63, wv = t >> 6;
    const int nb = blockIdx.x * 32;
    for (int i = t; i < 32 * 64; i += 256) hl[i] = h[(size_t)(nb + (i >> 6)) * 64 + (i & 63)];
    __syncthreads();

    float alr[8][NATTR];
    #pragma unroll
    for (int i = 0; i < 8; ++i) {
        const float* ap = attrs + (size_t)(nb + wv + 4 * i) * NATTR;
        #pragma unroll
        for (int v = 0; v < NATTR; ++v) alr[i][v] = ap[v];
    }

    float acc[8] = {0.f, 0.f, 0.f, 0.f, 0.f, 0.f, 0.f, 0.f};
    #pragma unroll 1
    for (int u4 = 0; u4 < 16; ++u4) {
        const int u0 = u4 * 4;
        float4 hu[8];
        #pragma unroll
        for (int i = 0; i < 8; ++i)
            hu[i] = *reinterpret_cast<const float4*>(&hl[(wv + 4 * i) * 64 + u0]);
        #pragma unroll
        for (int uu = 0; uu < 4; ++uu) {
            float tmp[8] = {0.f, 0.f, 0.f, 0.f, 0.f, 0.f, 0.f, 0.f};
            #pragma unroll
            for (int v = 0; v < NATTR; ++v) {
                const float wk = Wskip[((u0 + uu) * NATTR + v) * 64 + lane];
                #pragma unroll
                for (int i = 0; i < 8; ++i) tmp[i] += alr[i][v] * wk;
            }
            #pragma unroll
            for (int i = 0; i < 8; ++i) {
                const float huv = (uu == 0) ? hu[i].x : (uu == 1) ? hu[i].y
                                 : (uu == 2) ? hu[i].z : hu[i].w;
                acc[i] += huv * tmp[i];
            }
        }
    }
    const float scale = 0.03952847075210474f;  // 1/sqrt(640)
    #pragma unroll
    for (int i = 0; i < 8; ++i)
        sc[(size_t)(nb + wv + 4 * i) * 64 + lane] = acc[i] * scale;
}

// ---------------------------------------------------------------------------
extern "C" void kernel_launch(void* const* d_in, const int* in_sizes, int n_in,
                              void* d_out, int out_size, void* d_ws, size_t ws_size,
                              hipStream_t stream) {
    const float* node_attrs = (const float*)d_in[0];
    const float* node_feats = (const float*)d_in[1];
    const float* edge_attrs = (const float*)d_in[2];
    const float* edge_feats = (const float*)d_in[3];
    const int*   edge_index = (const int*)d_in[4];
    const float* W_lin1 = (const float*)d_in[5];
    const float* W_r0 = (const float*)d_in[6];
    const float* W_r1 = (const float*)d_in[7];
    const float* W_r2 = (const float*)d_in[8];
    const float* W_r3 = (const float*)d_in[9];
    const float* W_msg = (const float*)d_in[10];
    const float* W_skip = (const float*)d_in[11];

    float* out = (float*)d_out;                       // N x 576 (msg, transformed in place)
    float* sc  = out + (size_t)N_NODES * MSG_DIM;     // N x 64

    float* wsf = (float*)d_ws;
    float* Wc = wsf;                          // 2048 floats
    float* h  = wsf + 2048;                   // N*64
    int* wsi   = (int*)(wsf + 2048 + (size_t)N_NODES * 64);
    int* counts = wsi;                        // N
    int* start  = wsi + N_NODES;              // N
    int* cursor = wsi + 2 * N_NODES;          // N
    int*   snd_s = wsi + 3 * N_NODES;                 // E
    float* ef_s  = (float*)(snd_s + N_EDGES);         // E*8
    float* ea_s  = ef_s + (size_t)N_EDGES * 8;        // E*12
    const size_t need_bytes = ((size_t)2048 + (size_t)N_NODES * 64) * 4
                            + (size_t)(3 * N_NODES) * 4
                            + (size_t)N_EDGES * 4
                            + (size_t)N_EDGES * 8 * 4
                            + (size_t)N_EDGES * 12 * 4;
    const bool big_ws = ws_size >= need_bytes;
    int* perm = wsi + 3 * N_NODES;            // E (fallback path only)

    combine_radial<<<1, 256, 0, stream>>>(W_r0, W_r1, W_r2, W_r3, Wc);
    node_linear<<<1250, 256, 0, stream>>>(node_feats, W_lin1, h, counts);

    hist_kernel<<<(N_EDGES + 255) / 256, 256, 0, stream>>>(edge_index, counts);
    scan_kernel<<<1, 256, 0, stream>>>(counts, start, cursor);

    if (big_ws) {
        scatter_build<<<(N_EDGES + 255) / 256, 256, 0, stream>>>(
            edge_index, edge_feats, edge_attrs, cursor, snd_s, ef_s, ea_s);
        gather_sorted<<<(N_NODES + 1) / 2, 256, 0, stream>>>(
            ef_s, ea_s, snd_s, h, Wc, start, counts, out);
    } else {
        scatter_kernel<<<(N_EDGES + 255) / 256, 256, 0, stream>>>(edge_index, cursor, perm);
        gather_perm<<<(N_NODES + 3) / 4, 256, 0, stream>>>(
            edge_feats, edge_attrs, edge_index, h, Wc, start, counts, perm, out);
    }

    out_transform<<<2500, 256, 0, stream>>>(W_msg, out);
    skip_kernel<<<625, 256, 0, stream>>>(h, node_attrs, W_skip, sc);
}